// Round 12
// baseline (551.437 us; speedup 1.0000x reference)
//
#include <hip/hip_runtime.h>

typedef __attribute__((ext_vector_type(4))) float f32x4;
typedef __attribute__((ext_vector_type(8))) _Float16 f16x8;
typedef __attribute__((ext_vector_type(4))) _Float16 f16x4;

static __device__ __forceinline__ f32x4 mfma16f(f16x8 a, f16x8 b, f32x4 c) {
    return __builtin_amdgcn_mfma_f32_16x16x32_f16(a, b, c, 0, 0, 0);
}

// ---------------------------------------------------------------------------
// K0: fused f32 -> f16 hi/lo split for the 4 weight tensors (one launch).
// ---------------------------------------------------------------------------
__global__ void split_w4(const float* __restrict__ s0, const float* __restrict__ s1,
                         const float* __restrict__ s2, const float* __restrict__ s3,
                         _Float16* __restrict__ d0h, _Float16* __restrict__ d0l,
                         _Float16* __restrict__ d1h, _Float16* __restrict__ d1l,
                         _Float16* __restrict__ d2h, _Float16* __restrict__ d2l,
                         _Float16* __restrict__ d3h, _Float16* __restrict__ d3l) {
    const int seg = blockIdx.x >> 9;
    const int i = (blockIdx.x & 511) * 256 + threadIdx.x;
    const float* src = (seg == 0) ? s0 : (seg == 1) ? s1 : (seg == 2) ? s2 : s3;
    _Float16* dh = (seg == 0) ? d0h : (seg == 1) ? d1h : (seg == 2) ? d2h : d3h;
    _Float16* dl = (seg == 0) ? d0l : (seg == 1) ? d1l : (seg == 2) ? d2l : d3l;
    const float f = src[i];
    const _Float16 h = (_Float16)f;
    dh[i] = h;
    dl[i] = (_Float16)(f - (float)h);
}

// ---------------------------------------------------------------------------
// K1: QKV projection GEMM, split-f16 MFMA (3 terms) + BN fold.
// x transpose + hi/lo split FUSED into the staging loop (xsplit_t kernel
// eliminated): read x f32 coalesced (4 rows x f32x4/thread), convert, write
// f16x4 pairs into Ah/Al[hw][c]. Swapped operands D[o][n]; f16x4 q/k stores;
// BN fold precomputed into LDS.
//   q (pre-scaled 0.125), k : [b][h][n][64] f16 hi/lo
//   v                       : [b][h][64][n] f16 hi-only
// ---------------------------------------------------------------------------
__global__ __launch_bounds__(256) void qkv_mfma(
    const float* __restrict__ x,
    const _Float16* __restrict__ wqh, const _Float16* __restrict__ wql,
    const _Float16* __restrict__ wkh, const _Float16* __restrict__ wkl,
    const _Float16* __restrict__ wvh, const _Float16* __restrict__ wvl,
    const float* __restrict__ gq, const float* __restrict__ bq, const float* __restrict__ mq, const float* __restrict__ vq,
    const float* __restrict__ gk, const float* __restrict__ bk, const float* __restrict__ mk, const float* __restrict__ vk,
    const float* __restrict__ gv, const float* __restrict__ bv, const float* __restrict__ mv, const float* __restrict__ vv,
    _Float16* __restrict__ qh, _Float16* __restrict__ ql,
    _Float16* __restrict__ kh, _Float16* __restrict__ kl,
    _Float16* __restrict__ vt)
{
    __shared__ _Float16 Ah[128][72];
    __shared__ _Float16 Al[128][72];
    __shared__ float sc_l[128], tc_l[128];

    const int t = threadIdx.x;
    const int m0 = blockIdx.x * 128;
    const int bn = blockIdx.y;           // 0..11
    const int proj = bn >> 2;
    const int o0 = (bn & 3) * 128;       // [0,512)
    const int bimg = m0 >> 10;
    const int nb = m0 & 1023;

    const _Float16* Wh = (proj == 0) ? wqh : (proj == 1) ? wkh : wvh;
    const _Float16* Wl = (proj == 0) ? wql : (proj == 1) ? wkl : wvl;
    const float* G  = (proj == 0) ? gq : (proj == 1) ? gk : gv;
    const float* Bt = (proj == 0) ? bq : (proj == 1) ? bk : bv;
    const float* Mn = (proj == 0) ? mq : (proj == 1) ? mk : mv;
    const float* Vr = (proj == 0) ? vq : (proj == 1) ? vk : vv;

    if (t < 128) {
        const int o = o0 + t;
        float s = G[o] / sqrtf(Vr[o] + 1e-5f);
        float tt = Bt[o] - Mn[o] * s;
        if (proj == 0) { s *= 0.125f; tt *= 0.125f; }
        sc_l[t] = s; tc_l[t] = tt;
    }

    const int wave = t >> 6, lane = t & 63;
    const int quad = lane >> 4, l16 = lane & 15;
    const int wm = (wave >> 1) * 64, wn = (wave & 1) * 64;
    const int cq = t >> 4;        // c-quad 0..15 (covers 64 c per tile)
    const int hq = t & 15;        // hw-quad 0..15 (x4 = 64 hw per pass)

    f32x4 acc[4][4] = {};   // [nj (o-tile)][mi (n-tile)]

    for (int c0 = 0; c0 < 256; c0 += 64) {
        __syncthreads();
        // fused stage: x f32 -> transpose -> f16 hi/lo tiles [128 hw][64 c]
#pragma unroll
        for (int pass = 0; pass < 2; ++pass) {
            const int hwl = pass * 64 + hq * 4;
            f32x4 r[4];
#pragma unroll
            for (int j = 0; j < 4; ++j)
                r[j] = *(const f32x4*)&x[((size_t)(bimg * 256 + c0 + cq * 4 + j)) * 1024 + nb + hwl];
#pragma unroll
            for (int e = 0; e < 4; ++e) {
                f16x4 hv, lv;
#pragma unroll
                for (int j = 0; j < 4; ++j) {
                    const float f = r[j][e];
                    const _Float16 hh = (_Float16)f;
                    hv[j] = hh;
                    lv[j] = (_Float16)(f - (float)hh);
                }
                *(f16x4*)&Ah[hwl + e][cq * 4] = hv;
                *(f16x4*)&Al[hwl + e][cq * 4] = lv;
            }
        }
        __syncthreads();
#pragma unroll
        for (int kk = 0; kk < 2; ++kk) {
            f16x8 ah[4], al[4], bh[4], bl[4];
#pragma unroll
            for (int mi = 0; mi < 4; ++mi) {
                ah[mi] = *(const f16x8*)&Ah[wm + mi * 16 + l16][kk * 32 + quad * 8];
                al[mi] = *(const f16x8*)&Al[wm + mi * 16 + l16][kk * 32 + quad * 8];
            }
#pragma unroll
            for (int nj = 0; nj < 4; ++nj) {
                const size_t off = ((size_t)(o0 + wn + nj * 16 + l16)) * 256 + c0 + kk * 32 + quad * 8;
                bh[nj] = *(const f16x8*)(Wh + off);
                bl[nj] = *(const f16x8*)(Wl + off);
            }
            // swapped: D rows = channels o
#pragma unroll
            for (int nj = 0; nj < 4; ++nj)
#pragma unroll
                for (int mi = 0; mi < 4; ++mi) {
                    acc[nj][mi] = mfma16f(bh[nj], ah[mi], acc[nj][mi]);
                    acc[nj][mi] = mfma16f(bh[nj], al[mi], acc[nj][mi]);
                    acc[nj][mi] = mfma16f(bl[nj], ah[mi], acc[nj][mi]);
                }
        }
    }

    if (proj < 2) {
        _Float16* Oh = (proj == 0) ? qh : kh;
        _Float16* Ol = (proj == 0) ? ql : kl;
#pragma unroll
        for (int nj = 0; nj < 4; ++nj) {
            const int olb = wn + nj * 16 + quad * 4;     // local o base, 4 consecutive
            const int ob = o0 + olb;
            const int head = ob >> 6, d0 = ob & 63;
#pragma unroll
            for (int mi = 0; mi < 4; ++mi) {
                const int n = nb + wm + mi * 16 + l16;
                f16x4 hv, lv;
#pragma unroll
                for (int rr = 0; rr < 4; ++rr) {
                    const float val = acc[nj][mi][rr] * sc_l[olb + rr] + tc_l[olb + rr];
                    const _Float16 h = (_Float16)val;
                    hv[rr] = h;
                    lv[rr] = (_Float16)(val - (float)h);
                }
                const size_t off = (((size_t)(bimg * 8 + head)) * 1024 + n) * 64 + d0;
                *(f16x4*)(Oh + off) = hv;
                *(f16x4*)(Ol + off) = lv;
            }
        }
    } else {
#pragma unroll
        for (int nj = 0; nj < 4; ++nj) {
#pragma unroll
            for (int rr = 0; rr < 4; ++rr) {
                const int olb = wn + nj * 16 + quad * 4 + rr;
                const int o = o0 + olb;
                const int head = o >> 6, d = o & 63;
                const float s = sc_l[olb], tt = tc_l[olb];
#pragma unroll
                for (int mi = 0; mi < 4; ++mi) {
                    const int n = nb + wm + mi * 16 + l16;
                    const float val = acc[nj][mi][rr] * s + tt;
                    vt[(((size_t)(bimg * 8 + head)) * 64 + d) * 1024 + n] = (_Float16)val;
                }
            }
        }
    }
}

// ---------------------------------------------------------------------------
// K2: split-f16 MFMA flash attention + hardswish; fixed-max softmax (C=12).
// R10/R11 structure. LDS trimmed to exactly 40960 B (pt stride 76->72; 72
// gives only 2-way pt-write aliasing, free per bank arithmetic) so
// __launch_bounds__(256,4) fits 4 blocks/CU -> the 1024-block grid maps
// EXACTLY 4/CU with no straggler round (R11 ran 3/CU + a 256-block tail).
// hs stored hi-only f16.
// ---------------------------------------------------------------------------
__global__ __launch_bounds__(256, 4) void attn_mfma(
    const _Float16* __restrict__ qh, const _Float16* __restrict__ ql,
    const _Float16* __restrict__ kh, const _Float16* __restrict__ kl,
    const _Float16* __restrict__ vt,
    const float* __restrict__ emb,
    _Float16* __restrict__ hsh)
{
    __shared__ float    emb_s[1024];
    __shared__ _Float16 kth[64][72], ktl[64][72];   // [j][d] staged K tile
    __shared__ _Float16 pt[128][72];                // wave-private 32-row slabs

    const int t = threadIdx.x;
    const int bid = blockIdx.x;
    const int bh = bid & 127, qb = bid >> 7;
    const int b = bh >> 3, h = bh & 7;
    const int wave = t >> 6, lane = t & 63;
    const int quad = lane >> 4, l16 = lane & 15;
    const int q0 = qb * 128 + wave * 32;
    const float L2E = 1.44269504f;

    for (int i = t; i < 1024; i += 256) emb_s[i] = (8.0f * emb[i * 8 + h] - 12.0f) * L2E;

    const size_t base = (size_t)bh * 65536;   // q/k [n][64]; vT [64][n]

    f16x8 qfh[2][2], qfl[2][2];
#pragma unroll
    for (int mi = 0; mi < 2; ++mi)
#pragma unroll
        for (int kk = 0; kk < 2; ++kk) {
            const size_t off = base + (size_t)(q0 + mi * 16 + l16) * 64 + kk * 32 + quad * 8;
            qfh[mi][kk] = *(const f16x8*)(qh + off);
            qfl[mi][kk] = *(const f16x8*)(ql + off);
        }

    // per-row bias tables (xj in {2jb,2jb+1}; yj in {l16, 16+l16})
    int xiv[2][4], dy0[2][4], dy1[2][4];
#pragma unroll
    for (int mi = 0; mi < 2; ++mi)
#pragma unroll
        for (int r = 0; r < 4; ++r) {
            const int ig = q0 + mi * 16 + quad * 4 + r;
            const int xi = ig >> 5, yi = ig & 31;
            xiv[mi][r] = xi;
            dy0[mi][r] = abs(yi - l16);
            dy1[mi][r] = abs(yi - 16 - l16);
        }

    // K staging: thread covers rows {sr, 32+sr}, col chunk scs
    const int sr = t >> 3;            // 0..31
    const int scs = (t & 7) * 8;

    f16x8 pkh[2], pkl[2];             // K prefetch registers (tile jb)
#pragma unroll
    for (int p = 0; p < 2; ++p) {
        const size_t off = base + (size_t)(p * 32 + sr) * 64 + scs;   // jb = 0
        pkh[p] = *(const f16x8*)(kh + off);
        pkl[p] = *(const f16x8*)(kl + off);
    }

    f32x4 ao[2][4] = {};
    float lsum[2][4] = {};

    for (int jb = 0; jb < 16; ++jb) {
        __syncthreads();   // prior tile's LDS reads done (also orders emb_s at jb=0)
#pragma unroll
        for (int p = 0; p < 2; ++p) {
            *(f16x8*)&kth[p * 32 + sr][scs] = pkh[p];
            *(f16x8*)&ktl[p * 32 + sr][scs] = pkl[p];
        }
        __syncthreads();
        if (jb < 15) {     // K(jb+1) prefetch; latency hides behind compute
#pragma unroll
            for (int p = 0; p < 2; ++p) {
                const size_t off = base + (size_t)((jb + 1) * 64 + p * 32 + sr) * 64 + scs;
                pkh[p] = *(const f16x8*)(kh + off);
                pkl[p] = *(const f16x8*)(kl + off);
            }
        }

        // ---- S = Q K^T (3 f16 terms; K frags from LDS) ----
        f32x4 as[2][4] = {};
#pragma unroll
        for (int kk = 0; kk < 2; ++kk) {
            f16x8 kfh[4], kfl[4];
#pragma unroll
            for (int nj = 0; nj < 4; ++nj) {
                kfh[nj] = *(const f16x8*)&kth[nj * 16 + l16][kk * 32 + quad * 8];
                kfl[nj] = *(const f16x8*)&ktl[nj * 16 + l16][kk * 32 + quad * 8];
            }
#pragma unroll
            for (int mi = 0; mi < 2; ++mi)
#pragma unroll
                for (int nj = 0; nj < 4; ++nj) {
                    as[mi][nj] = mfma16f(qfh[mi][kk], kfh[nj], as[mi][nj]);
                    as[mi][nj] = mfma16f(qfh[mi][kk], kfl[nj], as[mi][nj]);
                    as[mi][nj] = mfma16f(qfl[mi][kk], kfh[nj], as[mi][nj]);
                }
        }

        // ---- p = exp2(S*log2e + bias'), lane-local sum, P -> LDS (f16) ----
        const int xj0 = jb * 2, xj1 = jb * 2 + 1;
#pragma unroll
        for (int mi = 0; mi < 2; ++mi) {
#pragma unroll
            for (int r = 0; r < 4; ++r) {
                const int dxa = abs(xiv[mi][r] - xj0) << 5;
                const int dxb = abs(xiv[mi][r] - xj1) << 5;
                const int prow = wave * 32 + mi * 16 + quad * 4 + r;
                const float p0 = exp2f(fmaf(as[mi][0][r], L2E, emb_s[dxa + dy0[mi][r]]));
                const float p1 = exp2f(fmaf(as[mi][1][r], L2E, emb_s[dxa + dy1[mi][r]]));
                const float p2 = exp2f(fmaf(as[mi][2][r], L2E, emb_s[dxb + dy0[mi][r]]));
                const float p3 = exp2f(fmaf(as[mi][3][r], L2E, emb_s[dxb + dy1[mi][r]]));
                lsum[mi][r] += (p0 + p1) + (p2 + p3);
                pt[prow][0 * 16 + l16] = (_Float16)p0;
                pt[prow][1 * 16 + l16] = (_Float16)p1;
                pt[prow][2 * 16 + l16] = (_Float16)p2;
                pt[prow][3 * 16 + l16] = (_Float16)p3;
            }
        }
        // no barrier: pt slab is wave-private; same-wave DS ops are in-order

        // ---- O += P V (single f16 term; V frags loaded at use) ----
#pragma unroll
        for (int kk = 0; kk < 2; ++kk) {
            f16x8 pa[2], vf[4];
#pragma unroll
            for (int mi = 0; mi < 2; ++mi)
                pa[mi] = *(const f16x8*)&pt[wave * 32 + mi * 16 + l16][kk * 32 + quad * 8];
#pragma unroll
            for (int dj = 0; dj < 4; ++dj) {
                const size_t off = base + (size_t)(dj * 16 + l16) * 1024 + jb * 64 + kk * 32 + quad * 8;
                vf[dj] = *(const f16x8*)(vt + off);
            }
#pragma unroll
            for (int mi = 0; mi < 2; ++mi)
#pragma unroll
                for (int dj = 0; dj < 4; ++dj)
                    ao[mi][dj] = mfma16f(pa[mi], vf[dj], ao[mi][dj]);
        }
    }

    // final cross-lane sum, normalize, hardswish, f16 hi-only store
#pragma unroll
    for (int mi = 0; mi < 2; ++mi) {
#pragma unroll
        for (int r = 0; r < 4; ++r) {
            float l = lsum[mi][r];
#pragma unroll
            for (int msk = 1; msk < 16; msk <<= 1)
                l += __shfl_xor(l, msk, 64);
            const float inv = 1.0f / l;
            const int ig = q0 + mi * 16 + quad * 4 + r;
#pragma unroll
            for (int dj = 0; dj < 4; ++dj) {
                const float o = ao[mi][dj][r] * inv;
                const float hsw = o * fminf(fmaxf(o + 3.0f, 0.0f), 6.0f) * (1.0f / 6.0f);
                hsh[((size_t)(b * 1024 + ig)) * 512 + h * 64 + dj * 16 + l16] = (_Float16)hsw;
            }
        }
    }
}

// ---------------------------------------------------------------------------
// K3: output projection GEMM, split-f16 MFMA — 2 TERMS (hs hi-only).
// 64m x 128o tiles (grid 256x2 = 512 blocks -> 2 blocks/CU exact).
// ---------------------------------------------------------------------------
__global__ __launch_bounds__(256) void out_mfma(
    const _Float16* __restrict__ hsh,
    const _Float16* __restrict__ woh, const _Float16* __restrict__ wol,
    const float* __restrict__ b_out, const float* __restrict__ go, const float* __restrict__ bo,
    const float* __restrict__ mo, const float* __restrict__ vo, float* __restrict__ y)
{
    __shared__ _Float16 Ah[64][72];

    const int t = threadIdx.x;
    const int m0 = blockIdx.x * 64;
    const int o0 = blockIdx.y * 128;
    const int bimg = m0 >> 10, nb = m0 & 1023;
    const int wave = t >> 6, lane = t & 63;
    const int quad = lane >> 4, l16 = lane & 15;
    const int wm = (wave >> 1) * 32, wn = (wave & 1) * 64;

    f32x4 acc[2][4] = {};

    for (int c0 = 0; c0 < 512; c0 += 64) {
        __syncthreads();
        {
            const int r = t >> 2;                 // 64 rows, 4 lanes/row
            const int cs = (t & 3) * 16;
            *(f16x8*)&Ah[r][cs]     = *(const f16x8*)(hsh + ((size_t)(m0 + r)) * 512 + c0 + cs);
            *(f16x8*)&Ah[r][cs + 8] = *(const f16x8*)(hsh + ((size_t)(m0 + r)) * 512 + c0 + cs + 8);
        }
        __syncthreads();
#pragma unroll
        for (int kk = 0; kk < 2; ++kk) {
            f16x8 ah[2], bh[4], bl[4];
#pragma unroll
            for (int mi = 0; mi < 2; ++mi)
                ah[mi] = *(const f16x8*)&Ah[wm + mi * 16 + l16][kk * 32 + quad * 8];
#pragma unroll
            for (int nj = 0; nj < 4; ++nj) {
                const size_t off = ((size_t)(o0 + wn + nj * 16 + l16)) * 512 + c0 + kk * 32 + quad * 8;
                bh[nj] = *(const f16x8*)(woh + off);
                bl[nj] = *(const f16x8*)(wol + off);
            }
#pragma unroll
            for (int mi = 0; mi < 2; ++mi)
#pragma unroll
                for (int nj = 0; nj < 4; ++nj) {
                    acc[mi][nj] = mfma16f(ah[mi], bh[nj], acc[mi][nj]);
                    acc[mi][nj] = mfma16f(ah[mi], bl[nj], acc[mi][nj]);
                }
        }
    }

#pragma unroll
    for (int nj = 0; nj < 4; ++nj) {
        const int o = o0 + wn + nj * 16 + l16;
        const float s = go[o] / sqrtf(vo[o] + 1e-5f);
        const float tt = bo[o] - mo[o] * s;
        const float bf = b_out[o];
#pragma unroll
        for (int mi = 0; mi < 2; ++mi) {
            const int hw = nb + wm + mi * 16 + quad * 4;
            f32x4 v4;
#pragma unroll
            for (int rr = 0; rr < 4; ++rr) v4[rr] = (acc[mi][nj][rr] + bf) * s + tt;
            *(f32x4*)&y[((size_t)(bimg * 256 + o)) * 1024 + hw] = v4;
        }
    }
}

extern "C" void kernel_launch(void* const* d_in, const int* in_sizes, int n_in,
                              void* d_out, int out_size, void* d_ws, size_t ws_size,
                              hipStream_t stream) {
    const float* x     = (const float*)d_in[0];
    const float* wq    = (const float*)d_in[1];
    const float* gq    = (const float*)d_in[2];
    const float* bq    = (const float*)d_in[3];
    const float* mq    = (const float*)d_in[4];
    const float* vq    = (const float*)d_in[5];
    const float* wk    = (const float*)d_in[6];
    const float* gk    = (const float*)d_in[7];
    const float* bk    = (const float*)d_in[8];
    const float* mk    = (const float*)d_in[9];
    const float* vk    = (const float*)d_in[10];
    const float* wv    = (const float*)d_in[11];
    const float* gv    = (const float*)d_in[12];
    const float* bv    = (const float*)d_in[13];
    const float* mv    = (const float*)d_in[14];
    const float* vv    = (const float*)d_in[15];
    const float* emb   = (const float*)d_in[16];
    const float* w_out = (const float*)d_in[17];
    const float* b_out = (const float*)d_in[18];
    const float* go    = (const float*)d_in[19];
    const float* bo    = (const float*)d_in[20];
    const float* mo    = (const float*)d_in[21];
    const float* vo    = (const float*)d_in[22];
    // d_in[23] = pos_indices — computed analytically in-kernel, unused.

    // Workspace (in _Float16 elements); peak < proven 136.3 MB.
    _Float16* us = (_Float16*)d_ws;
    _Float16* hsh = us;                        // [16][1024][512] (hi-only)
    _Float16* wsp = us + 16777216;             // weight splits, 8 x 131072
    _Float16* wqh = wsp,            *wql = wsp + 131072;
    _Float16* wkh = wsp + 262144,   *wkl = wsp + 393216;
    _Float16* wvh = wsp + 524288,   *wvl = wsp + 655360;
    _Float16* woh = wsp + 786432,   *wol = wsp + 917504;
    _Float16* qv  = us + 17825792;
    _Float16* qhw = qv,             *qlw = qv + 8388608;   // [16][8][1024][64]
    _Float16* khw = qv + 16777216,  *klw = qv + 25165824;  // [16][8][1024][64]
    _Float16* vtw = qv + 33554432;                          // [16][8][64][1024]

    split_w4<<<2048, 256, 0, stream>>>(wq, wk, wv, w_out,
                                       wqh, wql, wkh, wkl, wvh, wvl, woh, wol);

    qkv_mfma<<<dim3(128, 12), 256, 0, stream>>>(
        x, wqh, wql, wkh, wkl, wvh, wvl,
        gq, bq, mq, vq, gk, bk, mk, vk, gv, bv, mv, vv,
        qhw, qlw, khw, klw, vtw);

    attn_mfma<<<1024, 256, 0, stream>>>(
        qhw, qlw, khw, klw, vtw, emb, hsh);

    out_mfma<<<dim3(256, 2), 256, 0, stream>>>(
        hsh, woh, wol, b_out, go, bo, mo, vo, (float*)d_out);
}

// Round 13
// 354.213 us; speedup vs baseline: 1.5568x; 1.5568x over previous
//
#include <hip/hip_runtime.h>

typedef __attribute__((ext_vector_type(4))) float f32x4;
typedef __attribute__((ext_vector_type(8))) _Float16 f16x8;
typedef __attribute__((ext_vector_type(4))) _Float16 f16x4;

static __device__ __forceinline__ f32x4 mfma16f(f16x8 a, f16x8 b, f32x4 c) {
    return __builtin_amdgcn_mfma_f32_16x16x32_f16(a, b, c, 0, 0, 0);
}

// ---------------------------------------------------------------------------
// K0a: fused f32 -> f16 hi/lo split for the 4 weight tensors (one launch).
// ---------------------------------------------------------------------------
__global__ void split_w4(const float* __restrict__ s0, const float* __restrict__ s1,
                         const float* __restrict__ s2, const float* __restrict__ s3,
                         _Float16* __restrict__ d0h, _Float16* __restrict__ d0l,
                         _Float16* __restrict__ d1h, _Float16* __restrict__ d1l,
                         _Float16* __restrict__ d2h, _Float16* __restrict__ d2l,
                         _Float16* __restrict__ d3h, _Float16* __restrict__ d3l) {
    const int seg = blockIdx.x >> 9;
    const int i = (blockIdx.x & 511) * 256 + threadIdx.x;
    const float* src = (seg == 0) ? s0 : (seg == 1) ? s1 : (seg == 2) ? s2 : s3;
    _Float16* dh = (seg == 0) ? d0h : (seg == 1) ? d1h : (seg == 2) ? d2h : d3h;
    _Float16* dl = (seg == 0) ? d0l : (seg == 1) ? d1l : (seg == 2) ? d2l : d3l;
    const float f = src[i];
    const _Float16 h = (_Float16)f;
    dh[i] = h;
    dl[i] = (_Float16)(f - (float)h);
}

// ---------------------------------------------------------------------------
// K0b: x [16][256][1024] f32 -> xth/xtl [16][1024][256] f16 hi/lo
// 32x32 LDS tile transpose; f16x4 (8B) coalesced stores. (R11 version —
// the R12 fusion into qkv was net negative: x f32 re-read per bn-block.)
// ---------------------------------------------------------------------------
__global__ __launch_bounds__(256) void xsplit_t(
    const float* __restrict__ x, _Float16* __restrict__ xth, _Float16* __restrict__ xtl)
{
    __shared__ float lt[32][36];
    const int t = threadIdx.x;
    const int c0 = blockIdx.x * 32, hw0 = blockIdx.y * 32, b = blockIdx.z;
    {
        const int cl = t >> 3, hw4 = (t & 7) * 4;
        *(f32x4*)&lt[cl][hw4] = *(const f32x4*)&x[((size_t)(b * 256 + c0 + cl)) * 1024 + hw0 + hw4];
    }
    __syncthreads();
    {
        const int hwl = t >> 3, c4 = (t & 7) * 4;
        f16x4 hv, lv;
#pragma unroll
        for (int e = 0; e < 4; ++e) {
            const float f = lt[c4 + e][hwl];
            const _Float16 h = (_Float16)f;
            hv[e] = h;
            lv[e] = (_Float16)(f - (float)h);
        }
        const size_t off = ((size_t)(b * 1024 + hw0 + hwl)) * 256 + c0 + c4;
        *(f16x4*)(xth + off) = hv;
        *(f16x4*)(xtl + off) = lv;
    }
}

// ---------------------------------------------------------------------------
// K1: QKV projection GEMM, split-f16 MFMA + BN fold. (R11 structure —
// LDS-staged x tiles; swapped operands D[o][n]; f16x4 q/k stores; BN fold
// precomputed into LDS.)  NEW: V projection uses 2 TERMS (wh*xh + wh*xl;
// dropped wl*xh contributes ~2.4e-4, equal to V's hi-only storage error).
//   q (pre-scaled 0.125), k : [b][h][n][64] f16 hi/lo  (3 terms)
//   v                       : [b][h][64][n] f16 hi-only (2 terms)
// ---------------------------------------------------------------------------
__global__ __launch_bounds__(256) void qkv_mfma(
    const _Float16* __restrict__ xth, const _Float16* __restrict__ xtl,
    const _Float16* __restrict__ wqh, const _Float16* __restrict__ wql,
    const _Float16* __restrict__ wkh, const _Float16* __restrict__ wkl,
    const _Float16* __restrict__ wvh, const _Float16* __restrict__ wvl,
    const float* __restrict__ gq, const float* __restrict__ bq, const float* __restrict__ mq, const float* __restrict__ vq,
    const float* __restrict__ gk, const float* __restrict__ bk, const float* __restrict__ mk, const float* __restrict__ vk,
    const float* __restrict__ gv, const float* __restrict__ bv, const float* __restrict__ mv, const float* __restrict__ vv,
    _Float16* __restrict__ qh, _Float16* __restrict__ ql,
    _Float16* __restrict__ kh, _Float16* __restrict__ kl,
    _Float16* __restrict__ vt)
{
    __shared__ _Float16 Ah[128][72];
    __shared__ _Float16 Al[128][72];
    __shared__ float sc_l[128], tc_l[128];

    const int t = threadIdx.x;
    const int m0 = blockIdx.x * 128;
    const int bn = blockIdx.y;           // 0..11
    const int proj = bn >> 2;
    const int o0 = (bn & 3) * 128;       // [0,512)
    const int bimg = m0 >> 10;
    const int nb = m0 & 1023;

    const _Float16* Wh = (proj == 0) ? wqh : (proj == 1) ? wkh : wvh;
    const _Float16* Wl = (proj == 0) ? wql : (proj == 1) ? wkl : wvl;
    const float* G  = (proj == 0) ? gq : (proj == 1) ? gk : gv;
    const float* Bt = (proj == 0) ? bq : (proj == 1) ? bk : bv;
    const float* Mn = (proj == 0) ? mq : (proj == 1) ? mk : mv;
    const float* Vr = (proj == 0) ? vq : (proj == 1) ? vk : vv;

    if (t < 128) {
        const int o = o0 + t;
        float s = G[o] / sqrtf(Vr[o] + 1e-5f);
        float tt = Bt[o] - Mn[o] * s;
        if (proj == 0) { s *= 0.125f; tt *= 0.125f; }
        sc_l[t] = s; tc_l[t] = tt;
    }

    const int wave = t >> 6, lane = t & 63;
    const int quad = lane >> 4, l16 = lane & 15;
    const int wm = (wave >> 1) * 64, wn = (wave & 1) * 64;

    f32x4 acc[4][4] = {};   // [nj (o-tile)][mi (n-tile)]

    for (int c0 = 0; c0 < 256; c0 += 64) {
        __syncthreads();
        {   // stage x hi/lo tiles [128 n][64 c] (coalesced: 8 lanes x 16B per row)
            int r = t >> 3;
            const int cs = (t & 7) * 8;
#pragma unroll
            for (int p = 0; p < 4; ++p, r += 32) {
                const size_t off = ((size_t)(bimg * 1024 + nb + r)) * 256 + c0 + cs;
                *(f16x8*)&Ah[r][cs] = *(const f16x8*)(xth + off);
                *(f16x8*)&Al[r][cs] = *(const f16x8*)(xtl + off);
            }
        }
        __syncthreads();
#pragma unroll
        for (int kk = 0; kk < 2; ++kk) {
            f16x8 ah[4], al[4], bh[4], bl[4];
#pragma unroll
            for (int mi = 0; mi < 4; ++mi) {
                ah[mi] = *(const f16x8*)&Ah[wm + mi * 16 + l16][kk * 32 + quad * 8];
                al[mi] = *(const f16x8*)&Al[wm + mi * 16 + l16][kk * 32 + quad * 8];
            }
#pragma unroll
            for (int nj = 0; nj < 4; ++nj) {
                const size_t off = ((size_t)(o0 + wn + nj * 16 + l16)) * 256 + c0 + kk * 32 + quad * 8;
                bh[nj] = *(const f16x8*)(Wh + off);
                if (proj < 2) bl[nj] = *(const f16x8*)(Wl + off);
            }
            if (proj < 2) {
#pragma unroll
                for (int nj = 0; nj < 4; ++nj)
#pragma unroll
                    for (int mi = 0; mi < 4; ++mi) {
                        acc[nj][mi] = mfma16f(bh[nj], ah[mi], acc[nj][mi]);
                        acc[nj][mi] = mfma16f(bh[nj], al[mi], acc[nj][mi]);
                        acc[nj][mi] = mfma16f(bl[nj], ah[mi], acc[nj][mi]);
                    }
            } else {   // V: 2 terms
#pragma unroll
                for (int nj = 0; nj < 4; ++nj)
#pragma unroll
                    for (int mi = 0; mi < 4; ++mi) {
                        acc[nj][mi] = mfma16f(bh[nj], ah[mi], acc[nj][mi]);
                        acc[nj][mi] = mfma16f(bh[nj], al[mi], acc[nj][mi]);
                    }
            }
        }
    }

    if (proj < 2) {
        _Float16* Oh = (proj == 0) ? qh : kh;
        _Float16* Ol = (proj == 0) ? ql : kl;
#pragma unroll
        for (int nj = 0; nj < 4; ++nj) {
            const int olb = wn + nj * 16 + quad * 4;     // local o base, 4 consecutive
            const int ob = o0 + olb;
            const int head = ob >> 6, d0 = ob & 63;
#pragma unroll
            for (int mi = 0; mi < 4; ++mi) {
                const int n = nb + wm + mi * 16 + l16;
                f16x4 hv, lv;
#pragma unroll
                for (int rr = 0; rr < 4; ++rr) {
                    const float val = acc[nj][mi][rr] * sc_l[olb + rr] + tc_l[olb + rr];
                    const _Float16 h = (_Float16)val;
                    hv[rr] = h;
                    lv[rr] = (_Float16)(val - (float)h);
                }
                const size_t off = (((size_t)(bimg * 8 + head)) * 1024 + n) * 64 + d0;
                *(f16x4*)(Oh + off) = hv;
                *(f16x4*)(Ol + off) = lv;
            }
        }
    } else {
#pragma unroll
        for (int nj = 0; nj < 4; ++nj) {
#pragma unroll
            for (int rr = 0; rr < 4; ++rr) {
                const int olb = wn + nj * 16 + quad * 4 + rr;
                const int o = o0 + olb;
                const int head = o >> 6, d = o & 63;
                const float s = sc_l[olb], tt = tc_l[olb];
#pragma unroll
                for (int mi = 0; mi < 4; ++mi) {
                    const int n = nb + wm + mi * 16 + l16;
                    const float val = acc[nj][mi][rr] * s + tt;
                    vt[(((size_t)(bimg * 8 + head)) * 64 + d) * 1024 + n] = (_Float16)val;
                }
            }
        }
    }
}

// ---------------------------------------------------------------------------
// K2: split-f16 MFMA flash attention + hardswish; fixed-max softmax (C=12).
// EXACT R11 kernel (149.5 µs config): K hi/lo LDS-staged, register prefetch
// of jb+1, V loaded at use, wave-private P slab (stride 76), exp2 softmax
// with hoisted bias tables, hs hi-only stores, __launch_bounds__(256,3).
// NOTE: (256,4) tried in R12 — unified VGPR+AGPR budget forced arch VGPR
// to 64 and spilled (+1GB HBM traffic). Do not raise occupancy here.
// ---------------------------------------------------------------------------
__global__ __launch_bounds__(256, 3) void attn_mfma(
    const _Float16* __restrict__ qh, const _Float16* __restrict__ ql,
    const _Float16* __restrict__ kh, const _Float16* __restrict__ kl,
    const _Float16* __restrict__ vt,
    const float* __restrict__ emb,
    _Float16* __restrict__ hsh)
{
    __shared__ float    emb_s[1024];
    __shared__ _Float16 kth[64][72], ktl[64][72];   // [j][d] staged K tile
    __shared__ _Float16 pt[128][76];                // wave-private 32-row slabs

    const int t = threadIdx.x;
    const int bid = blockIdx.x;
    const int bh = bid & 127, qb = bid >> 7;
    const int b = bh >> 3, h = bh & 7;
    const int wave = t >> 6, lane = t & 63;
    const int quad = lane >> 4, l16 = lane & 15;
    const int q0 = qb * 128 + wave * 32;
    const float L2E = 1.44269504f;

    for (int i = t; i < 1024; i += 256) emb_s[i] = (8.0f * emb[i * 8 + h] - 12.0f) * L2E;

    const size_t base = (size_t)bh * 65536;   // q/k [n][64]; vT [64][n]

    f16x8 qfh[2][2], qfl[2][2];
#pragma unroll
    for (int mi = 0; mi < 2; ++mi)
#pragma unroll
        for (int kk = 0; kk < 2; ++kk) {
            const size_t off = base + (size_t)(q0 + mi * 16 + l16) * 64 + kk * 32 + quad * 8;
            qfh[mi][kk] = *(const f16x8*)(qh + off);
            qfl[mi][kk] = *(const f16x8*)(ql + off);
        }

    // per-row bias tables (xj in {2jb,2jb+1}; yj in {l16, 16+l16})
    int xiv[2][4], dy0[2][4], dy1[2][4];
#pragma unroll
    for (int mi = 0; mi < 2; ++mi)
#pragma unroll
        for (int r = 0; r < 4; ++r) {
            const int ig = q0 + mi * 16 + quad * 4 + r;
            const int xi = ig >> 5, yi = ig & 31;
            xiv[mi][r] = xi;
            dy0[mi][r] = abs(yi - l16);
            dy1[mi][r] = abs(yi - 16 - l16);
        }

    // K staging: thread covers rows {sr, 32+sr}, col chunk scs
    const int sr = t >> 3;            // 0..31
    const int scs = (t & 7) * 8;

    f16x8 pkh[2], pkl[2];             // K prefetch registers (tile jb)
#pragma unroll
    for (int p = 0; p < 2; ++p) {
        const size_t off = base + (size_t)(p * 32 + sr) * 64 + scs;   // jb = 0
        pkh[p] = *(const f16x8*)(kh + off);
        pkl[p] = *(const f16x8*)(kl + off);
    }

    f32x4 ao[2][4] = {};
    float lsum[2][4] = {};

    for (int jb = 0; jb < 16; ++jb) {
        __syncthreads();   // prior tile's LDS reads done (also orders emb_s at jb=0)
#pragma unroll
        for (int p = 0; p < 2; ++p) {
            *(f16x8*)&kth[p * 32 + sr][scs] = pkh[p];
            *(f16x8*)&ktl[p * 32 + sr][scs] = pkl[p];
        }
        __syncthreads();
        if (jb < 15) {     // K(jb+1) prefetch; latency hides behind compute
#pragma unroll
            for (int p = 0; p < 2; ++p) {
                const size_t off = base + (size_t)((jb + 1) * 64 + p * 32 + sr) * 64 + scs;
                pkh[p] = *(const f16x8*)(kh + off);
                pkl[p] = *(const f16x8*)(kl + off);
            }
        }

        // ---- S = Q K^T (3 f16 terms; K frags from LDS) ----
        f32x4 as[2][4] = {};
#pragma unroll
        for (int kk = 0; kk < 2; ++kk) {
            f16x8 kfh[4], kfl[4];
#pragma unroll
            for (int nj = 0; nj < 4; ++nj) {
                kfh[nj] = *(const f16x8*)&kth[nj * 16 + l16][kk * 32 + quad * 8];
                kfl[nj] = *(const f16x8*)&ktl[nj * 16 + l16][kk * 32 + quad * 8];
            }
#pragma unroll
            for (int mi = 0; mi < 2; ++mi)
#pragma unroll
                for (int nj = 0; nj < 4; ++nj) {
                    as[mi][nj] = mfma16f(qfh[mi][kk], kfh[nj], as[mi][nj]);
                    as[mi][nj] = mfma16f(qfh[mi][kk], kfl[nj], as[mi][nj]);
                    as[mi][nj] = mfma16f(qfl[mi][kk], kfh[nj], as[mi][nj]);
                }
        }

        // ---- p = exp2(S*log2e + bias'), lane-local sum, P -> LDS (f16) ----
        const int xj0 = jb * 2, xj1 = jb * 2 + 1;
#pragma unroll
        for (int mi = 0; mi < 2; ++mi) {
#pragma unroll
            for (int r = 0; r < 4; ++r) {
                const int dxa = abs(xiv[mi][r] - xj0) << 5;
                const int dxb = abs(xiv[mi][r] - xj1) << 5;
                const int prow = wave * 32 + mi * 16 + quad * 4 + r;
                const float p0 = exp2f(fmaf(as[mi][0][r], L2E, emb_s[dxa + dy0[mi][r]]));
                const float p1 = exp2f(fmaf(as[mi][1][r], L2E, emb_s[dxa + dy1[mi][r]]));
                const float p2 = exp2f(fmaf(as[mi][2][r], L2E, emb_s[dxb + dy0[mi][r]]));
                const float p3 = exp2f(fmaf(as[mi][3][r], L2E, emb_s[dxb + dy1[mi][r]]));
                lsum[mi][r] += (p0 + p1) + (p2 + p3);
                pt[prow][0 * 16 + l16] = (_Float16)p0;
                pt[prow][1 * 16 + l16] = (_Float16)p1;
                pt[prow][2 * 16 + l16] = (_Float16)p2;
                pt[prow][3 * 16 + l16] = (_Float16)p3;
            }
        }
        // no barrier: pt slab is wave-private; same-wave DS ops are in-order

        // ---- O += P V (single f16 term; V frags loaded at use) ----
#pragma unroll
        for (int kk = 0; kk < 2; ++kk) {
            f16x8 pa[2], vf[4];
#pragma unroll
            for (int mi = 0; mi < 2; ++mi)
                pa[mi] = *(const f16x8*)&pt[wave * 32 + mi * 16 + l16][kk * 32 + quad * 8];
#pragma unroll
            for (int dj = 0; dj < 4; ++dj) {
                const size_t off = base + (size_t)(dj * 16 + l16) * 1024 + jb * 64 + kk * 32 + quad * 8;
                vf[dj] = *(const f16x8*)(vt + off);
            }
#pragma unroll
            for (int mi = 0; mi < 2; ++mi)
#pragma unroll
                for (int dj = 0; dj < 4; ++dj)
                    ao[mi][dj] = mfma16f(pa[mi], vf[dj], ao[mi][dj]);
        }
    }

    // final cross-lane sum, normalize, hardswish, f16 hi-only store
#pragma unroll
    for (int mi = 0; mi < 2; ++mi) {
#pragma unroll
        for (int r = 0; r < 4; ++r) {
            float l = lsum[mi][r];
#pragma unroll
            for (int msk = 1; msk < 16; msk <<= 1)
                l += __shfl_xor(l, msk, 64);
            const float inv = 1.0f / l;
            const int ig = q0 + mi * 16 + quad * 4 + r;
#pragma unroll
            for (int dj = 0; dj < 4; ++dj) {
                const float o = ao[mi][dj][r] * inv;
                const float hsw = o * fminf(fmaxf(o + 3.0f, 0.0f), 6.0f) * (1.0f / 6.0f);
                hsh[((size_t)(b * 1024 + ig)) * 512 + h * 64 + dj * 16 + l16] = (_Float16)hsw;
            }
        }
    }
}

// ---------------------------------------------------------------------------
// K3: output projection GEMM, split-f16 MFMA — 2 TERMS (hs hi-only).
// 64m x 128o tiles (grid 256x2 = 512 blocks -> 2 blocks/CU exact). (R11)
// ---------------------------------------------------------------------------
__global__ __launch_bounds__(256) void out_mfma(
    const _Float16* __restrict__ hsh,
    const _Float16* __restrict__ woh, const _Float16* __restrict__ wol,
    const float* __restrict__ b_out, const float* __restrict__ go, const float* __restrict__ bo,
    const float* __restrict__ mo, const float* __restrict__ vo, float* __restrict__ y)
{
    __shared__ _Float16 Ah[64][72];

    const int t = threadIdx.x;
    const int m0 = blockIdx.x * 64;
    const int o0 = blockIdx.y * 128;
    const int bimg = m0 >> 10, nb = m0 & 1023;
    const int wave = t >> 6, lane = t & 63;
    const int quad = lane >> 4, l16 = lane & 15;
    const int wm = (wave >> 1) * 32, wn = (wave & 1) * 64;

    f32x4 acc[2][4] = {};

    for (int c0 = 0; c0 < 512; c0 += 64) {
        __syncthreads();
        {
            const int r = t >> 2;                 // 64 rows, 4 lanes/row
            const int cs = (t & 3) * 16;
            *(f16x8*)&Ah[r][cs]     = *(const f16x8*)(hsh + ((size_t)(m0 + r)) * 512 + c0 + cs);
            *(f16x8*)&Ah[r][cs + 8] = *(const f16x8*)(hsh + ((size_t)(m0 + r)) * 512 + c0 + cs + 8);
        }
        __syncthreads();
#pragma unroll
        for (int kk = 0; kk < 2; ++kk) {
            f16x8 ah[2], bh[4], bl[4];
#pragma unroll
            for (int mi = 0; mi < 2; ++mi)
                ah[mi] = *(const f16x8*)&Ah[wm + mi * 16 + l16][kk * 32 + quad * 8];
#pragma unroll
            for (int nj = 0; nj < 4; ++nj) {
                const size_t off = ((size_t)(o0 + wn + nj * 16 + l16)) * 512 + c0 + kk * 32 + quad * 8;
                bh[nj] = *(const f16x8*)(woh + off);
                bl[nj] = *(const f16x8*)(wol + off);
            }
#pragma unroll
            for (int mi = 0; mi < 2; ++mi)
#pragma unroll
                for (int nj = 0; nj < 4; ++nj) {
                    acc[mi][nj] = mfma16f(ah[mi], bh[nj], acc[mi][nj]);
                    acc[mi][nj] = mfma16f(ah[mi], bl[nj], acc[mi][nj]);
                }
        }
    }

#pragma unroll
    for (int nj = 0; nj < 4; ++nj) {
        const int o = o0 + wn + nj * 16 + l16;
        const float s = go[o] / sqrtf(vo[o] + 1e-5f);
        const float tt = bo[o] - mo[o] * s;
        const float bf = b_out[o];
#pragma unroll
        for (int mi = 0; mi < 2; ++mi) {
            const int hw = nb + wm + mi * 16 + quad * 4;
            f32x4 v4;
#pragma unroll
            for (int rr = 0; rr < 4; ++rr) v4[rr] = (acc[mi][nj][rr] + bf) * s + tt;
            *(f32x4*)&y[((size_t)(bimg * 256 + o)) * 1024 + hw] = v4;
        }
    }
}

extern "C" void kernel_launch(void* const* d_in, const int* in_sizes, int n_in,
                              void* d_out, int out_size, void* d_ws, size_t ws_size,
                              hipStream_t stream) {
    const float* x     = (const float*)d_in[0];
    const float* wq    = (const float*)d_in[1];
    const float* gq    = (const float*)d_in[2];
    const float* bq    = (const float*)d_in[3];
    const float* mq    = (const float*)d_in[4];
    const float* vq    = (const float*)d_in[5];
    const float* wk    = (const float*)d_in[6];
    const float* gk    = (const float*)d_in[7];
    const float* bk    = (const float*)d_in[8];
    const float* mk    = (const float*)d_in[9];
    const float* vk    = (const float*)d_in[10];
    const float* wv    = (const float*)d_in[11];
    const float* gv    = (const float*)d_in[12];
    const float* bv    = (const float*)d_in[13];
    const float* mv    = (const float*)d_in[14];
    const float* vv    = (const float*)d_in[15];
    const float* emb   = (const float*)d_in[16];
    const float* w_out = (const float*)d_in[17];
    const float* b_out = (const float*)d_in[18];
    const float* go    = (const float*)d_in[19];
    const float* bo    = (const float*)d_in[20];
    const float* mo    = (const float*)d_in[21];
    const float* vo    = (const float*)d_in[22];
    // d_in[23] = pos_indices — computed analytically in-kernel, unused.

    // Workspace (in _Float16 elements); peak < proven 136.3 MB.
    _Float16* us = (_Float16*)d_ws;
    // Union region [0, 16,777,216): xth/xtl early, hsh late (x dead by attn).
    _Float16* xth = us;                        // [16][1024][256]
    _Float16* xtl = us + 4194304;
    _Float16* hsh = us;                        // [16][1024][512] (hi-only)
    _Float16* wsp = us + 16777216;             // weight splits, 8 x 131072
    _Float16* wqh = wsp,            *wql = wsp + 131072;
    _Float16* wkh = wsp + 262144,   *wkl = wsp + 393216;
    _Float16* wvh = wsp + 524288,   *wvl = wsp + 655360;
    _Float16* woh = wsp + 786432,   *wol = wsp + 917504;
    _Float16* qv  = us + 17825792;
    _Float16* qhw = qv,             *qlw = qv + 8388608;   // [16][8][1024][64]
    _Float16* khw = qv + 16777216,  *klw = qv + 25165824;  // [16][8][1024][64]
    _Float16* vtw = qv + 33554432;                          // [16][8][64][1024]

    split_w4<<<2048, 256, 0, stream>>>(wq, wk, wv, w_out,
                                       wqh, wql, wkh, wkl, wvh, wvl, woh, wol);

    xsplit_t<<<dim3(8, 32, 16), 256, 0, stream>>>(x, xth, xtl);

    qkv_mfma<<<dim3(128, 12), 256, 0, stream>>>(
        xth, xtl, wqh, wql, wkh, wkl, wvh, wvl,
        gq, bq, mq, vq, gk, bk, mk, vk, gv, bv, mv, vv,
        qhw, qlw, khw, klw, vtw);

    attn_mfma<<<1024, 256, 0, stream>>>(
        qhw, qlw, khw, klw, vtw, emb, hsh);

    out_mfma<<<dim3(256, 2), 256, 0, stream>>>(
        hsh, woh, wol, b_out, go, bo, mo, vo, (float*)d_out);
}

// Round 14
// 332.945 us; speedup vs baseline: 1.6562x; 1.0639x over previous
//
#include <hip/hip_runtime.h>

typedef __attribute__((ext_vector_type(4))) float f32x4;
typedef __attribute__((ext_vector_type(8))) _Float16 f16x8;
typedef __attribute__((ext_vector_type(4))) _Float16 f16x4;

static __device__ __forceinline__ f32x4 mfma16f(f16x8 a, f16x8 b, f32x4 c) {
    return __builtin_amdgcn_mfma_f32_16x16x32_f16(a, b, c, 0, 0, 0);
}

// ---------------------------------------------------------------------------
// K0a: fused f32 -> f16 hi/lo split for the 4 weight tensors (one launch).
// ---------------------------------------------------------------------------
__global__ void split_w4(const float* __restrict__ s0, const float* __restrict__ s1,
                         const float* __restrict__ s2, const float* __restrict__ s3,
                         _Float16* __restrict__ d0h, _Float16* __restrict__ d0l,
                         _Float16* __restrict__ d1h, _Float16* __restrict__ d1l,
                         _Float16* __restrict__ d2h, _Float16* __restrict__ d2l,
                         _Float16* __restrict__ d3h, _Float16* __restrict__ d3l) {
    const int seg = blockIdx.x >> 9;
    const int i = (blockIdx.x & 511) * 256 + threadIdx.x;
    const float* src = (seg == 0) ? s0 : (seg == 1) ? s1 : (seg == 2) ? s2 : s3;
    _Float16* dh = (seg == 0) ? d0h : (seg == 1) ? d1h : (seg == 2) ? d2h : d3h;
    _Float16* dl = (seg == 0) ? d0l : (seg == 1) ? d1l : (seg == 2) ? d2l : d3l;
    const float f = src[i];
    const _Float16 h = (_Float16)f;
    dh[i] = h;
    dl[i] = (_Float16)(f - (float)h);
}

// ---------------------------------------------------------------------------
// K0b: x [16][256][1024] f32 -> xth/xtl [16][1024][256] f16 hi/lo
// 32x32 LDS tile transpose; f16x4 (8B) coalesced stores.
// ---------------------------------------------------------------------------
__global__ __launch_bounds__(256) void xsplit_t(
    const float* __restrict__ x, _Float16* __restrict__ xth, _Float16* __restrict__ xtl)
{
    __shared__ float lt[32][36];
    const int t = threadIdx.x;
    const int c0 = blockIdx.x * 32, hw0 = blockIdx.y * 32, b = blockIdx.z;
    {
        const int cl = t >> 3, hw4 = (t & 7) * 4;
        *(f32x4*)&lt[cl][hw4] = *(const f32x4*)&x[((size_t)(b * 256 + c0 + cl)) * 1024 + hw0 + hw4];
    }
    __syncthreads();
    {
        const int hwl = t >> 3, c4 = (t & 7) * 4;
        f16x4 hv, lv;
#pragma unroll
        for (int e = 0; e < 4; ++e) {
            const float f = lt[c4 + e][hwl];
            const _Float16 h = (_Float16)f;
            hv[e] = h;
            lv[e] = (_Float16)(f - (float)h);
        }
        const size_t off = ((size_t)(b * 1024 + hw0 + hwl)) * 256 + c0 + c4;
        *(f16x4*)(xth + off) = hv;
        *(f16x4*)(xtl + off) = lv;
    }
}

// ---------------------------------------------------------------------------
// K1: QKV projection GEMM, split-f16 MFMA + BN fold.
// Grid SWAPPED to (12 bn, 128 m0): the 12 blocks sharing an x-slice are
// dispatch-adjacent -> L2/L3 temporal locality on the staged x tile.
// q/k: swapped operands D[o][n], 3 terms, f16x4 hi/lo stores.
// v:   NON-swapped D[n][o], 2 terms -> 4 consecutive n per reg -> 16 f16x4
//      stores (was 64 scalar). BN fold precomputed into LDS.
// ---------------------------------------------------------------------------
__global__ __launch_bounds__(256) void qkv_mfma(
    const _Float16* __restrict__ xth, const _Float16* __restrict__ xtl,
    const _Float16* __restrict__ wqh, const _Float16* __restrict__ wql,
    const _Float16* __restrict__ wkh, const _Float16* __restrict__ wkl,
    const _Float16* __restrict__ wvh, const _Float16* __restrict__ wvl,
    const float* __restrict__ gq, const float* __restrict__ bq, const float* __restrict__ mq, const float* __restrict__ vq,
    const float* __restrict__ gk, const float* __restrict__ bk, const float* __restrict__ mk, const float* __restrict__ vk,
    const float* __restrict__ gv, const float* __restrict__ bv, const float* __restrict__ mv, const float* __restrict__ vv,
    _Float16* __restrict__ qh, _Float16* __restrict__ ql,
    _Float16* __restrict__ kh, _Float16* __restrict__ kl,
    _Float16* __restrict__ vt)
{
    __shared__ _Float16 Ah[128][72];
    __shared__ _Float16 Al[128][72];
    __shared__ float sc_l[128], tc_l[128];

    const int t = threadIdx.x;
    const int bn = blockIdx.x;           // 0..11
    const int m0 = blockIdx.y * 128;
    const int proj = bn >> 2;
    const int o0 = (bn & 3) * 128;       // [0,512)
    const int bimg = m0 >> 10;
    const int nb = m0 & 1023;

    const _Float16* Wh = (proj == 0) ? wqh : (proj == 1) ? wkh : wvh;
    const _Float16* Wl = (proj == 0) ? wql : (proj == 1) ? wkl : wvl;
    const float* G  = (proj == 0) ? gq : (proj == 1) ? gk : gv;
    const float* Bt = (proj == 0) ? bq : (proj == 1) ? bk : bv;
    const float* Mn = (proj == 0) ? mq : (proj == 1) ? mk : mv;
    const float* Vr = (proj == 0) ? vq : (proj == 1) ? vk : vv;

    if (t < 128) {
        const int o = o0 + t;
        float s = G[o] / sqrtf(Vr[o] + 1e-5f);
        float tt = Bt[o] - Mn[o] * s;
        if (proj == 0) { s *= 0.125f; tt *= 0.125f; }
        sc_l[t] = s; tc_l[t] = tt;
    }

    const int wave = t >> 6, lane = t & 63;
    const int quad = lane >> 4, l16 = lane & 15;
    const int wm = (wave >> 1) * 64, wn = (wave & 1) * 64;

    f32x4 acc[4][4] = {};   // q/k: [nj][mi] ; v: [mi][nj]

    for (int c0 = 0; c0 < 256; c0 += 64) {
        __syncthreads();
        {   // stage x hi/lo tiles [128 n][64 c]
            int r = t >> 3;
            const int cs = (t & 7) * 8;
#pragma unroll
            for (int p = 0; p < 4; ++p, r += 32) {
                const size_t off = ((size_t)(bimg * 1024 + nb + r)) * 256 + c0 + cs;
                *(f16x8*)&Ah[r][cs] = *(const f16x8*)(xth + off);
                *(f16x8*)&Al[r][cs] = *(const f16x8*)(xtl + off);
            }
        }
        __syncthreads();
#pragma unroll
        for (int kk = 0; kk < 2; ++kk) {
            f16x8 ah[4], al[4], bh[4], bl[4];
#pragma unroll
            for (int mi = 0; mi < 4; ++mi) {
                ah[mi] = *(const f16x8*)&Ah[wm + mi * 16 + l16][kk * 32 + quad * 8];
                al[mi] = *(const f16x8*)&Al[wm + mi * 16 + l16][kk * 32 + quad * 8];
            }
#pragma unroll
            for (int nj = 0; nj < 4; ++nj) {
                const size_t off = ((size_t)(o0 + wn + nj * 16 + l16)) * 256 + c0 + kk * 32 + quad * 8;
                bh[nj] = *(const f16x8*)(Wh + off);
                if (proj < 2) bl[nj] = *(const f16x8*)(Wl + off);
            }
            if (proj < 2) {   // swapped: D rows = channels o, 3 terms
#pragma unroll
                for (int nj = 0; nj < 4; ++nj)
#pragma unroll
                    for (int mi = 0; mi < 4; ++mi) {
                        acc[nj][mi] = mfma16f(bh[nj], ah[mi], acc[nj][mi]);
                        acc[nj][mi] = mfma16f(bh[nj], al[mi], acc[nj][mi]);
                        acc[nj][mi] = mfma16f(bl[nj], ah[mi], acc[nj][mi]);
                    }
            } else {          // V: NON-swapped, D rows = n, 2 terms
#pragma unroll
                for (int mi = 0; mi < 4; ++mi)
#pragma unroll
                    for (int nj = 0; nj < 4; ++nj) {
                        acc[mi][nj] = mfma16f(ah[mi], bh[nj], acc[mi][nj]);
                        acc[mi][nj] = mfma16f(al[mi], bh[nj], acc[mi][nj]);
                    }
            }
        }
    }

    if (proj < 2) {
        _Float16* Oh = (proj == 0) ? qh : kh;
        _Float16* Ol = (proj == 0) ? ql : kl;
#pragma unroll
        for (int nj = 0; nj < 4; ++nj) {
            const int olb = wn + nj * 16 + quad * 4;     // local o base, 4 consecutive
            const int ob = o0 + olb;
            const int head = ob >> 6, d0 = ob & 63;
#pragma unroll
            for (int mi = 0; mi < 4; ++mi) {
                const int n = nb + wm + mi * 16 + l16;
                f16x4 hv, lv;
#pragma unroll
                for (int rr = 0; rr < 4; ++rr) {
                    const float val = acc[nj][mi][rr] * sc_l[olb + rr] + tc_l[olb + rr];
                    const _Float16 h = (_Float16)val;
                    hv[rr] = h;
                    lv[rr] = (_Float16)(val - (float)h);
                }
                const size_t off = (((size_t)(bimg * 8 + head)) * 1024 + n) * 64 + d0;
                *(f16x4*)(Oh + off) = hv;
                *(f16x4*)(Ol + off) = lv;
            }
        }
    } else {
        // non-swapped: rows n = nb+wm+mi*16+quad*4+rr (4 consecutive per reg),
        // cols o = o0+wn+nj*16+l16 -> f16x4 stores along n into vt[d][n].
#pragma unroll
        for (int nj = 0; nj < 4; ++nj) {
            const int olb = wn + nj * 16 + l16;
            const int o = o0 + olb;
            const int head = o >> 6, d = o & 63;
            const float s = sc_l[olb], tt = tc_l[olb];
#pragma unroll
            for (int mi = 0; mi < 4; ++mi) {
                const int n0 = nb + wm + mi * 16 + quad * 4;
                f16x4 v4;
#pragma unroll
                for (int rr = 0; rr < 4; ++rr) v4[rr] = (_Float16)(acc[mi][nj][rr] * s + tt);
                *(f16x4*)(vt + (((size_t)(bimg * 8 + head)) * 64 + d) * 1024 + n0) = v4;
            }
        }
    }
}

// ---------------------------------------------------------------------------
// K2: split-f16 MFMA flash attention + hardswish; fixed-max softmax (C=12).
// R13 structure + V tile now LDS-STAGED (vt is pre-transposed in global, so
// staging is a straight copy — no R6-style transpose conflicts) with its own
// 8-VGPR register prefetch alongside K's. Kills the 32x per-wave V refetch.
// LDS 51.2 KB -> still exactly 3 blocks/CU. (256,4) is a known spill trap.
// ---------------------------------------------------------------------------
__global__ __launch_bounds__(256, 3) void attn_mfma(
    const _Float16* __restrict__ qh, const _Float16* __restrict__ ql,
    const _Float16* __restrict__ kh, const _Float16* __restrict__ kl,
    const _Float16* __restrict__ vt,
    const float* __restrict__ emb,
    _Float16* __restrict__ hsh)
{
    __shared__ float    emb_s[1024];
    __shared__ _Float16 kth[64][72], ktl[64][72];   // [j][d] staged K tile
    __shared__ _Float16 vts[64][72];                // [d][j] staged V tile
    __shared__ _Float16 pt[128][76];                // wave-private 32-row slabs

    const int t = threadIdx.x;
    const int bid = blockIdx.x;
    const int bh = bid & 127, qb = bid >> 7;
    const int b = bh >> 3, h = bh & 7;
    const int wave = t >> 6, lane = t & 63;
    const int quad = lane >> 4, l16 = lane & 15;
    const int q0 = qb * 128 + wave * 32;
    const float L2E = 1.44269504f;

    for (int i = t; i < 1024; i += 256) emb_s[i] = (8.0f * emb[i * 8 + h] - 12.0f) * L2E;

    const size_t base = (size_t)bh * 65536;   // q/k [n][64]; vT [64][n]

    f16x8 qfh[2][2], qfl[2][2];
#pragma unroll
    for (int mi = 0; mi < 2; ++mi)
#pragma unroll
        for (int kk = 0; kk < 2; ++kk) {
            const size_t off = base + (size_t)(q0 + mi * 16 + l16) * 64 + kk * 32 + quad * 8;
            qfh[mi][kk] = *(const f16x8*)(qh + off);
            qfl[mi][kk] = *(const f16x8*)(ql + off);
        }

    // per-row bias tables (xj in {2jb,2jb+1}; yj in {l16, 16+l16})
    int xiv[2][4], dy0[2][4], dy1[2][4];
#pragma unroll
    for (int mi = 0; mi < 2; ++mi)
#pragma unroll
        for (int r = 0; r < 4; ++r) {
            const int ig = q0 + mi * 16 + quad * 4 + r;
            const int xi = ig >> 5, yi = ig & 31;
            xiv[mi][r] = xi;
            dy0[mi][r] = abs(yi - l16);
            dy1[mi][r] = abs(yi - 16 - l16);
        }

    // K staging: thread covers rows {sr, 32+sr}, col chunk scs
    const int sr = t >> 3;            // 0..31
    const int scs = (t & 7) * 8;
    // V staging: thread covers row rv, col chunk cv (+0, +8)
    const int rv = t >> 2;            // 0..63
    const int cv = (t & 3) * 16;

    f16x8 pkh[2], pkl[2], pvv[2];     // prefetch registers (tile jb)
#pragma unroll
    for (int p = 0; p < 2; ++p) {
        const size_t koff = base + (size_t)(p * 32 + sr) * 64 + scs;      // jb = 0
        pkh[p] = *(const f16x8*)(kh + koff);
        pkl[p] = *(const f16x8*)(kl + koff);
        pvv[p] = *(const f16x8*)(vt + base + (size_t)rv * 1024 + cv + p * 8);
    }

    f32x4 ao[2][4] = {};
    float lsum[2][4] = {};

    for (int jb = 0; jb < 16; ++jb) {
        __syncthreads();   // prior tile's LDS reads done (also orders emb_s at jb=0)
#pragma unroll
        for (int p = 0; p < 2; ++p) {
            *(f16x8*)&kth[p * 32 + sr][scs] = pkh[p];
            *(f16x8*)&ktl[p * 32 + sr][scs] = pkl[p];
            *(f16x8*)&vts[rv][cv + p * 8] = pvv[p];
        }
        __syncthreads();
        if (jb < 15) {     // (jb+1) prefetch; latency hides behind compute
#pragma unroll
            for (int p = 0; p < 2; ++p) {
                const size_t koff = base + (size_t)((jb + 1) * 64 + p * 32 + sr) * 64 + scs;
                pkh[p] = *(const f16x8*)(kh + koff);
                pkl[p] = *(const f16x8*)(kl + koff);
                pvv[p] = *(const f16x8*)(vt + base + (size_t)rv * 1024 + (jb + 1) * 64 + cv + p * 8);
            }
        }

        // ---- S = Q K^T (3 f16 terms; K frags from LDS) ----
        f32x4 as[2][4] = {};
#pragma unroll
        for (int kk = 0; kk < 2; ++kk) {
            f16x8 kfh[4], kfl[4];
#pragma unroll
            for (int nj = 0; nj < 4; ++nj) {
                kfh[nj] = *(const f16x8*)&kth[nj * 16 + l16][kk * 32 + quad * 8];
                kfl[nj] = *(const f16x8*)&ktl[nj * 16 + l16][kk * 32 + quad * 8];
            }
#pragma unroll
            for (int mi = 0; mi < 2; ++mi)
#pragma unroll
                for (int nj = 0; nj < 4; ++nj) {
                    as[mi][nj] = mfma16f(qfh[mi][kk], kfh[nj], as[mi][nj]);
                    as[mi][nj] = mfma16f(qfh[mi][kk], kfl[nj], as[mi][nj]);
                    as[mi][nj] = mfma16f(qfl[mi][kk], kfh[nj], as[mi][nj]);
                }
        }

        // ---- p = exp2(S*log2e + bias'), lane-local sum, P -> LDS (f16) ----
        const int xj0 = jb * 2, xj1 = jb * 2 + 1;
#pragma unroll
        for (int mi = 0; mi < 2; ++mi) {
#pragma unroll
            for (int r = 0; r < 4; ++r) {
                const int dxa = abs(xiv[mi][r] - xj0) << 5;
                const int dxb = abs(xiv[mi][r] - xj1) << 5;
                const int prow = wave * 32 + mi * 16 + quad * 4 + r;
                const float p0 = exp2f(fmaf(as[mi][0][r], L2E, emb_s[dxa + dy0[mi][r]]));
                const float p1 = exp2f(fmaf(as[mi][1][r], L2E, emb_s[dxa + dy1[mi][r]]));
                const float p2 = exp2f(fmaf(as[mi][2][r], L2E, emb_s[dxb + dy0[mi][r]]));
                const float p3 = exp2f(fmaf(as[mi][3][r], L2E, emb_s[dxb + dy1[mi][r]]));
                lsum[mi][r] += (p0 + p1) + (p2 + p3);
                pt[prow][0 * 16 + l16] = (_Float16)p0;
                pt[prow][1 * 16 + l16] = (_Float16)p1;
                pt[prow][2 * 16 + l16] = (_Float16)p2;
                pt[prow][3 * 16 + l16] = (_Float16)p3;
            }
        }
        // no barrier: pt slab is wave-private; same-wave DS ops are in-order

        // ---- O += P V (single f16 term; V frags from LDS) ----
#pragma unroll
        for (int kk = 0; kk < 2; ++kk) {
            f16x8 pa[2], vf[4];
#pragma unroll
            for (int mi = 0; mi < 2; ++mi)
                pa[mi] = *(const f16x8*)&pt[wave * 32 + mi * 16 + l16][kk * 32 + quad * 8];
#pragma unroll
            for (int dj = 0; dj < 4; ++dj)
                vf[dj] = *(const f16x8*)&vts[dj * 16 + l16][kk * 32 + quad * 8];
#pragma unroll
            for (int mi = 0; mi < 2; ++mi)
#pragma unroll
                for (int dj = 0; dj < 4; ++dj)
                    ao[mi][dj] = mfma16f(pa[mi], vf[dj], ao[mi][dj]);
        }
    }

    // final cross-lane sum, normalize, hardswish, f16 hi-only store
#pragma unroll
    for (int mi = 0; mi < 2; ++mi) {
#pragma unroll
        for (int r = 0; r < 4; ++r) {
            float l = lsum[mi][r];
#pragma unroll
            for (int msk = 1; msk < 16; msk <<= 1)
                l += __shfl_xor(l, msk, 64);
            const float inv = 1.0f / l;
            const int ig = q0 + mi * 16 + quad * 4 + r;
#pragma unroll
            for (int dj = 0; dj < 4; ++dj) {
                const float o = ao[mi][dj][r] * inv;
                const float hsw = o * fminf(fmaxf(o + 3.0f, 0.0f), 6.0f) * (1.0f / 6.0f);
                hsh[((size_t)(b * 1024 + ig)) * 512 + h * 64 + dj * 16 + l16] = (_Float16)hsw;
            }
        }
    }
}

// ---------------------------------------------------------------------------
// K3: output projection GEMM, split-f16 MFMA — 2 TERMS (hs hi-only).
// 64m x 128o tiles, BK=128 (halves barrier count: 8 vs 16). Grid (256,2).
// ---------------------------------------------------------------------------
__global__ __launch_bounds__(256) void out_mfma(
    const _Float16* __restrict__ hsh,
    const _Float16* __restrict__ woh, const _Float16* __restrict__ wol,
    const float* __restrict__ b_out, const float* __restrict__ go, const float* __restrict__ bo,
    const float* __restrict__ mo, const float* __restrict__ vo, float* __restrict__ y)
{
    __shared__ _Float16 Ah[64][136];

    const int t = threadIdx.x;
    const int m0 = blockIdx.x * 64;
    const int o0 = blockIdx.y * 128;
    const int bimg = m0 >> 10, nb = m0 & 1023;
    const int wave = t >> 6, lane = t & 63;
    const int quad = lane >> 4, l16 = lane & 15;
    const int wm = (wave >> 1) * 32, wn = (wave & 1) * 64;

    f32x4 acc[2][4] = {};

    for (int c0 = 0; c0 < 512; c0 += 128) {
        __syncthreads();
        {
            const int cs = (t & 7) * 16;
#pragma unroll
            for (int p = 0; p < 2; ++p) {
                const int r = (t >> 3) + p * 32;
                *(f16x8*)&Ah[r][cs]     = *(const f16x8*)(hsh + ((size_t)(m0 + r)) * 512 + c0 + cs);
                *(f16x8*)&Ah[r][cs + 8] = *(const f16x8*)(hsh + ((size_t)(m0 + r)) * 512 + c0 + cs + 8);
            }
        }
        __syncthreads();
#pragma unroll
        for (int kk = 0; kk < 4; ++kk) {
            f16x8 ah[2], bh[4], bl[4];
#pragma unroll
            for (int mi = 0; mi < 2; ++mi)
                ah[mi] = *(const f16x8*)&Ah[wm + mi * 16 + l16][kk * 32 + quad * 8];
#pragma unroll
            for (int nj = 0; nj < 4; ++nj) {
                const size_t off = ((size_t)(o0 + wn + nj * 16 + l16)) * 512 + c0 + kk * 32 + quad * 8;
                bh[nj] = *(const f16x8*)(woh + off);
                bl[nj] = *(const f16x8*)(wol + off);
            }
#pragma unroll
            for (int mi = 0; mi < 2; ++mi)
#pragma unroll
                for (int nj = 0; nj < 4; ++nj) {
                    acc[mi][nj] = mfma16f(ah[mi], bh[nj], acc[mi][nj]);
                    acc[mi][nj] = mfma16f(ah[mi], bl[nj], acc[mi][nj]);
                }
        }
    }

#pragma unroll
    for (int nj = 0; nj < 4; ++nj) {
        const int o = o0 + wn + nj * 16 + l16;
        const float s = go[o] / sqrtf(vo[o] + 1e-5f);
        const float tt = bo[o] - mo[o] * s;
        const float bf = b_out[o];
#pragma unroll
        for (int mi = 0; mi < 2; ++mi) {
            const int hw = nb + wm + mi * 16 + quad * 4;
            f32x4 v4;
#pragma unroll
            for (int rr = 0; rr < 4; ++rr) v4[rr] = (acc[mi][nj][rr] + bf) * s + tt;
            *(f32x4*)&y[((size_t)(bimg * 256 + o)) * 1024 + hw] = v4;
        }
    }
}

extern "C" void kernel_launch(void* const* d_in, const int* in_sizes, int n_in,
                              void* d_out, int out_size, void* d_ws, size_t ws_size,
                              hipStream_t stream) {
    const float* x     = (const float*)d_in[0];
    const float* wq    = (const float*)d_in[1];
    const float* gq    = (const float*)d_in[2];
    const float* bq    = (const float*)d_in[3];
    const float* mq    = (const float*)d_in[4];
    const float* vq    = (const float*)d_in[5];
    const float* wk    = (const float*)d_in[6];
    const float* gk    = (const float*)d_in[7];
    const float* bk    = (const float*)d_in[8];
    const float* mk    = (const float*)d_in[9];
    const float* vk    = (const float*)d_in[10];
    const float* wv    = (const float*)d_in[11];
    const float* gv    = (const float*)d_in[12];
    const float* bv    = (const float*)d_in[13];
    const float* mv    = (const float*)d_in[14];
    const float* vv    = (const float*)d_in[15];
    const float* emb   = (const float*)d_in[16];
    const float* w_out = (const float*)d_in[17];
    const float* b_out = (const float*)d_in[18];
    const float* go    = (const float*)d_in[19];
    const float* bo    = (const float*)d_in[20];
    const float* mo    = (const float*)d_in[21];
    const float* vo    = (const float*)d_in[22];
    // d_in[23] = pos_indices — computed analytically in-kernel, unused.

    // Workspace (in _Float16 elements); peak < proven 136.3 MB.
    _Float16* us = (_Float16*)d_ws;
    // Union region [0, 16,777,216): xth/xtl early, hsh late (x dead by attn).
    _Float16* xth = us;                        // [16][1024][256]
    _Float16* xtl = us + 4194304;
    _Float16* hsh = us;                        // [16][1024][512] (hi-only)
    _Float16* wsp = us + 16777216;             // weight splits, 8 x 131072
    _Float16* wqh = wsp,            *wql = wsp + 131072;
    _Float16* wkh = wsp + 262144,   *wkl = wsp + 393216;
    _Float16* wvh = wsp + 524288,   *wvl = wsp + 655360;
    _Float16* woh = wsp + 786432,   *wol = wsp + 917504;
    _Float16* qv  = us + 17825792;
    _Float16* qhw = qv,             *qlw = qv + 8388608;   // [16][8][1024][64]
    _Float16* khw = qv + 16777216,  *klw = qv + 25165824;  // [16][8][1024][64]
    _Float16* vtw = qv + 33554432;                          // [16][8][64][1024]

    split_w4<<<2048, 256, 0, stream>>>(wq, wk, wv, w_out,
                                       wqh, wql, wkh, wkl, wvh, wvl, woh, wol);

    xsplit_t<<<dim3(8, 32, 16), 256, 0, stream>>>(x, xth, xtl);

    qkv_mfma<<<dim3(12, 128), 256, 0, stream>>>(
        xth, xtl, wqh, wql, wkh, wkl, wvh, wvl,
        gq, bq, mq, vq, gk, bk, mk, vk, gv, bv, mv, vv,
        qhw, qlw, khw, klw, vtw);

    attn_mfma<<<1024, 256, 0, stream>>>(
        qhw, qlw, khw, klw, vtw, emb, hsh);

    out_mfma<<<dim3(256, 2), 256, 0, stream>>>(
        hsh, woh, wol, b_out, go, bo, mo, vo, (float*)d_out);
}

// Round 15
// 302.809 us; speedup vs baseline: 1.8211x; 1.0995x over previous
//
#include <hip/hip_runtime.h>

typedef __attribute__((ext_vector_type(4))) float f32x4;
typedef __attribute__((ext_vector_type(8))) _Float16 f16x8;
typedef __attribute__((ext_vector_type(4))) _Float16 f16x4;

static __device__ __forceinline__ f32x4 mfma16f(f16x8 a, f16x8 b, f32x4 c) {
    return __builtin_amdgcn_mfma_f32_16x16x32_f16(a, b, c, 0, 0, 0);
}

// ---------------------------------------------------------------------------
// K0: prep — fused weight hi/lo split (blocks 0..2047) + x transpose/split
// (blocks 2048..6143). One launch instead of two.
// ---------------------------------------------------------------------------
__global__ __launch_bounds__(256) void prep(
    const float* __restrict__ x,
    const float* __restrict__ s0, const float* __restrict__ s1,
    const float* __restrict__ s2, const float* __restrict__ s3,
    _Float16* __restrict__ d0h, _Float16* __restrict__ d0l,
    _Float16* __restrict__ d1h, _Float16* __restrict__ d1l,
    _Float16* __restrict__ d2h, _Float16* __restrict__ d2l,
    _Float16* __restrict__ d3h, _Float16* __restrict__ d3l,
    _Float16* __restrict__ xth, _Float16* __restrict__ xtl)
{
    __shared__ float lt[32][36];
    const int t = threadIdx.x;
    const int bid = blockIdx.x;
    if (bid < 2048) {
        const int seg = bid >> 9;
        const int i = (bid & 511) * 256 + t;
        const float* src = (seg == 0) ? s0 : (seg == 1) ? s1 : (seg == 2) ? s2 : s3;
        _Float16* dh = (seg == 0) ? d0h : (seg == 1) ? d1h : (seg == 2) ? d2h : d3h;
        _Float16* dl = (seg == 0) ? d0l : (seg == 1) ? d1l : (seg == 2) ? d2l : d3l;
        const float f = src[i];
        const _Float16 h = (_Float16)f;
        dh[i] = h;
        dl[i] = (_Float16)(f - (float)h);
    } else {
        const int bid2 = bid - 2048;
        const int c0 = (bid2 & 7) * 32, hw0 = ((bid2 >> 3) & 31) * 32, b = bid2 >> 8;
        {
            const int cl = t >> 3, hw4 = (t & 7) * 4;
            *(f32x4*)&lt[cl][hw4] = *(const f32x4*)&x[((size_t)(b * 256 + c0 + cl)) * 1024 + hw0 + hw4];
        }
        __syncthreads();
        {
            const int hwl = t >> 3, c4 = (t & 7) * 4;
            f16x4 hv, lv;
#pragma unroll
            for (int e = 0; e < 4; ++e) {
                const float f = lt[c4 + e][hwl];
                const _Float16 h = (_Float16)f;
                hv[e] = h;
                lv[e] = (_Float16)(f - (float)h);
            }
            const size_t off = ((size_t)(b * 1024 + hw0 + hwl)) * 256 + c0 + c4;
            *(f16x4*)(xth + off) = hv;
            *(f16x4*)(xtl + off) = lv;
        }
    }
}

// ---------------------------------------------------------------------------
// K1: QKV projection GEMM, split-f16 MFMA + BN fold.
// Grid (12 bn, 128 m0) — bn fastest for x-slice locality.
// q: 3 terms, hi/lo f16x4 stores.  k: 3-term math, HI-ONLY output (attn's
// QK is now q(hi+lo)·kh — the kl tensor is dead).  v: 2 terms, non-swapped
// D[n][o] epilogue, hi-only vt stores.
// ---------------------------------------------------------------------------
__global__ __launch_bounds__(256) void qkv_mfma(
    const _Float16* __restrict__ xth, const _Float16* __restrict__ xtl,
    const _Float16* __restrict__ wqh, const _Float16* __restrict__ wql,
    const _Float16* __restrict__ wkh, const _Float16* __restrict__ wkl,
    const _Float16* __restrict__ wvh, const _Float16* __restrict__ wvl,
    const float* __restrict__ gq, const float* __restrict__ bq, const float* __restrict__ mq, const float* __restrict__ vq,
    const float* __restrict__ gk, const float* __restrict__ bk, const float* __restrict__ mk, const float* __restrict__ vk,
    const float* __restrict__ gv, const float* __restrict__ bv, const float* __restrict__ mv, const float* __restrict__ vv,
    _Float16* __restrict__ qh, _Float16* __restrict__ ql,
    _Float16* __restrict__ kh,
    _Float16* __restrict__ vt)
{
    __shared__ _Float16 Ah[128][72];
    __shared__ _Float16 Al[128][72];
    __shared__ float sc_l[128], tc_l[128];

    const int t = threadIdx.x;
    const int bn = blockIdx.x;           // 0..11
    const int m0 = blockIdx.y * 128;
    const int proj = bn >> 2;
    const int o0 = (bn & 3) * 128;       // [0,512)
    const int bimg = m0 >> 10;
    const int nb = m0 & 1023;

    const _Float16* Wh = (proj == 0) ? wqh : (proj == 1) ? wkh : wvh;
    const _Float16* Wl = (proj == 0) ? wql : (proj == 1) ? wkl : wvl;
    const float* G  = (proj == 0) ? gq : (proj == 1) ? gk : gv;
    const float* Bt = (proj == 0) ? bq : (proj == 1) ? bk : bv;
    const float* Mn = (proj == 0) ? mq : (proj == 1) ? mk : mv;
    const float* Vr = (proj == 0) ? vq : (proj == 1) ? vk : vv;

    if (t < 128) {
        const int o = o0 + t;
        float s = G[o] / sqrtf(Vr[o] + 1e-5f);
        float tt = Bt[o] - Mn[o] * s;
        if (proj == 0) { s *= 0.125f; tt *= 0.125f; }
        sc_l[t] = s; tc_l[t] = tt;
    }

    const int wave = t >> 6, lane = t & 63;
    const int quad = lane >> 4, l16 = lane & 15;
    const int wm = (wave >> 1) * 64, wn = (wave & 1) * 64;

    f32x4 acc[4][4] = {};   // q/k: [nj][mi] ; v: [mi][nj]

    for (int c0 = 0; c0 < 256; c0 += 64) {
        __syncthreads();
        {   // stage x hi/lo tiles [128 n][64 c]
            int r = t >> 3;
            const int cs = (t & 7) * 8;
#pragma unroll
            for (int p = 0; p < 4; ++p, r += 32) {
                const size_t off = ((size_t)(bimg * 1024 + nb + r)) * 256 + c0 + cs;
                *(f16x8*)&Ah[r][cs] = *(const f16x8*)(xth + off);
                *(f16x8*)&Al[r][cs] = *(const f16x8*)(xtl + off);
            }
        }
        __syncthreads();
#pragma unroll
        for (int kk = 0; kk < 2; ++kk) {
            f16x8 ah[4], al[4], bh[4], bl[4];
#pragma unroll
            for (int mi = 0; mi < 4; ++mi) {
                ah[mi] = *(const f16x8*)&Ah[wm + mi * 16 + l16][kk * 32 + quad * 8];
                al[mi] = *(const f16x8*)&Al[wm + mi * 16 + l16][kk * 32 + quad * 8];
            }
#pragma unroll
            for (int nj = 0; nj < 4; ++nj) {
                const size_t off = ((size_t)(o0 + wn + nj * 16 + l16)) * 256 + c0 + kk * 32 + quad * 8;
                bh[nj] = *(const f16x8*)(Wh + off);
                if (proj < 2) bl[nj] = *(const f16x8*)(Wl + off);
            }
            if (proj < 2) {   // swapped: D rows = channels o, 3 terms
#pragma unroll
                for (int nj = 0; nj < 4; ++nj)
#pragma unroll
                    for (int mi = 0; mi < 4; ++mi) {
                        acc[nj][mi] = mfma16f(bh[nj], ah[mi], acc[nj][mi]);
                        acc[nj][mi] = mfma16f(bh[nj], al[mi], acc[nj][mi]);
                        acc[nj][mi] = mfma16f(bl[nj], ah[mi], acc[nj][mi]);
                    }
            } else {          // V: NON-swapped, D rows = n, 2 terms
#pragma unroll
                for (int mi = 0; mi < 4; ++mi)
#pragma unroll
                    for (int nj = 0; nj < 4; ++nj) {
                        acc[mi][nj] = mfma16f(ah[mi], bh[nj], acc[mi][nj]);
                        acc[mi][nj] = mfma16f(al[mi], bh[nj], acc[mi][nj]);
                    }
            }
        }
    }

    if (proj < 2) {
        _Float16* Oh = (proj == 0) ? qh : kh;
#pragma unroll
        for (int nj = 0; nj < 4; ++nj) {
            const int olb = wn + nj * 16 + quad * 4;     // local o base, 4 consecutive
            const int ob = o0 + olb;
            const int head = ob >> 6, d0 = ob & 63;
#pragma unroll
            for (int mi = 0; mi < 4; ++mi) {
                const int n = nb + wm + mi * 16 + l16;
                f16x4 hv, lv;
#pragma unroll
                for (int rr = 0; rr < 4; ++rr) {
                    const float val = acc[nj][mi][rr] * sc_l[olb + rr] + tc_l[olb + rr];
                    const _Float16 h = (_Float16)val;
                    hv[rr] = h;
                    lv[rr] = (_Float16)(val - (float)h);
                }
                const size_t off = (((size_t)(bimg * 8 + head)) * 1024 + n) * 64 + d0;
                *(f16x4*)(Oh + off) = hv;
                if (proj == 0) *(f16x4*)(ql + off) = lv;   // only q keeps the lo part
            }
        }
    } else {
#pragma unroll
        for (int nj = 0; nj < 4; ++nj) {
            const int olb = wn + nj * 16 + l16;
            const int o = o0 + olb;
            const int head = o >> 6, d = o & 63;
            const float s = sc_l[olb], tt = tc_l[olb];
#pragma unroll
            for (int mi = 0; mi < 4; ++mi) {
                const int n0 = nb + wm + mi * 16 + quad * 4;
                f16x4 v4;
#pragma unroll
                for (int rr = 0; rr < 4; ++rr) v4[rr] = (_Float16)(acc[mi][nj][rr] * s + tt);
                *(f16x4*)(vt + (((size_t)(bimg * 8 + head)) * 64 + d) * 1024 + n0) = v4;
            }
        }
    }
}

// ---------------------------------------------------------------------------
// K2: split-f16 MFMA flash attention + hardswish; fixed-max softmax (C=12).
// R14 structure with: (a) kl DROPPED — QK = qh*kh + ql*kh (full-precision Q
// against f16 K; S error ~1.5e-3 max, invisible at y) -> 25% less MFMA,
// half the K-frag LDS reads, 4 instead of 6 staging writes; (b) kth/vts
// row stride padded 72->76 (stride-38-dword rows: fragment reads hit
// distinct banks; stride 36 was 4-8-way). LDS 43 KB, 3 blocks/CU.
// (256,4) remains a spill trap — do not raise.
// ---------------------------------------------------------------------------
__global__ __launch_bounds__(256, 3) void attn_mfma(
    const _Float16* __restrict__ qh, const _Float16* __restrict__ ql,
    const _Float16* __restrict__ kh,
    const _Float16* __restrict__ vt,
    const float* __restrict__ emb,
    _Float16* __restrict__ hsh)
{
    __shared__ float    emb_s[1024];
    __shared__ _Float16 kth[64][76];                // [j][d] staged K tile (hi)
    __shared__ _Float16 vts[64][76];                // [d][j] staged V tile
    __shared__ _Float16 pt[128][76];                // wave-private 32-row slabs

    const int t = threadIdx.x;
    const int bid = blockIdx.x;
    const int bh = bid & 127, qb = bid >> 7;
    const int b = bh >> 3, h = bh & 7;
    const int wave = t >> 6, lane = t & 63;
    const int quad = lane >> 4, l16 = lane & 15;
    const int q0 = qb * 128 + wave * 32;
    const float L2E = 1.44269504f;

    for (int i = t; i < 1024; i += 256) emb_s[i] = (8.0f * emb[i * 8 + h] - 12.0f) * L2E;

    const size_t base = (size_t)bh * 65536;   // q/k [n][64]; vT [64][n]

    f16x8 qfh[2][2], qfl[2][2];
#pragma unroll
    for (int mi = 0; mi < 2; ++mi)
#pragma unroll
        for (int kk = 0; kk < 2; ++kk) {
            const size_t off = base + (size_t)(q0 + mi * 16 + l16) * 64 + kk * 32 + quad * 8;
            qfh[mi][kk] = *(const f16x8*)(qh + off);
            qfl[mi][kk] = *(const f16x8*)(ql + off);
        }

    // per-row bias tables (xj in {2jb,2jb+1}; yj in {l16, 16+l16})
    int xiv[2][4], dy0[2][4], dy1[2][4];
#pragma unroll
    for (int mi = 0; mi < 2; ++mi)
#pragma unroll
        for (int r = 0; r < 4; ++r) {
            const int ig = q0 + mi * 16 + quad * 4 + r;
            const int xi = ig >> 5, yi = ig & 31;
            xiv[mi][r] = xi;
            dy0[mi][r] = abs(yi - l16);
            dy1[mi][r] = abs(yi - 16 - l16);
        }

    // K staging: thread covers rows {sr, 32+sr}, col chunk scs
    const int sr = t >> 3;            // 0..31
    const int scs = (t & 7) * 8;
    // V staging: thread covers row rv, col chunk cv (+0, +8)
    const int rv = t >> 2;            // 0..63
    const int cv = (t & 3) * 16;

    f16x8 pkh[2], pvv[2];             // prefetch registers (tile jb)
#pragma unroll
    for (int p = 0; p < 2; ++p) {
        pkh[p] = *(const f16x8*)(kh + base + (size_t)(p * 32 + sr) * 64 + scs);   // jb = 0
        pvv[p] = *(const f16x8*)(vt + base + (size_t)rv * 1024 + cv + p * 8);
    }

    f32x4 ao[2][4] = {};
    float lsum[2][4] = {};

    for (int jb = 0; jb < 16; ++jb) {
        __syncthreads();   // prior tile's LDS reads done (also orders emb_s at jb=0)
#pragma unroll
        for (int p = 0; p < 2; ++p) {
            *(f16x8*)&kth[p * 32 + sr][scs] = pkh[p];
            *(f16x8*)&vts[rv][cv + p * 8] = pvv[p];
        }
        __syncthreads();
        if (jb < 15) {     // (jb+1) prefetch; latency hides behind compute
#pragma unroll
            for (int p = 0; p < 2; ++p) {
                pkh[p] = *(const f16x8*)(kh + base + (size_t)((jb + 1) * 64 + p * 32 + sr) * 64 + scs);
                pvv[p] = *(const f16x8*)(vt + base + (size_t)rv * 1024 + (jb + 1) * 64 + cv + p * 8);
            }
        }

        // ---- S = Q K^T (2 f16 terms: (qh+ql)*kh; K frags from LDS) ----
        f32x4 as[2][4] = {};
#pragma unroll
        for (int kk = 0; kk < 2; ++kk) {
            f16x8 kfh[4];
#pragma unroll
            for (int nj = 0; nj < 4; ++nj)
                kfh[nj] = *(const f16x8*)&kth[nj * 16 + l16][kk * 32 + quad * 8];
#pragma unroll
            for (int mi = 0; mi < 2; ++mi)
#pragma unroll
                for (int nj = 0; nj < 4; ++nj) {
                    as[mi][nj] = mfma16f(qfh[mi][kk], kfh[nj], as[mi][nj]);
                    as[mi][nj] = mfma16f(qfl[mi][kk], kfh[nj], as[mi][nj]);
                }
        }

        // ---- p = exp2(S*log2e + bias'), lane-local sum, P -> LDS (f16) ----
        const int xj0 = jb * 2, xj1 = jb * 2 + 1;
#pragma unroll
        for (int mi = 0; mi < 2; ++mi) {
#pragma unroll
            for (int r = 0; r < 4; ++r) {
                const int dxa = abs(xiv[mi][r] - xj0) << 5;
                const int dxb = abs(xiv[mi][r] - xj1) << 5;
                const int prow = wave * 32 + mi * 16 + quad * 4 + r;
                const float p0 = exp2f(fmaf(as[mi][0][r], L2E, emb_s[dxa + dy0[mi][r]]));
                const float p1 = exp2f(fmaf(as[mi][1][r], L2E, emb_s[dxa + dy1[mi][r]]));
                const float p2 = exp2f(fmaf(as[mi][2][r], L2E, emb_s[dxb + dy0[mi][r]]));
                const float p3 = exp2f(fmaf(as[mi][3][r], L2E, emb_s[dxb + dy1[mi][r]]));
                lsum[mi][r] += (p0 + p1) + (p2 + p3);
                pt[prow][0 * 16 + l16] = (_Float16)p0;
                pt[prow][1 * 16 + l16] = (_Float16)p1;
                pt[prow][2 * 16 + l16] = (_Float16)p2;
                pt[prow][3 * 16 + l16] = (_Float16)p3;
            }
        }
        // no barrier: pt slab is wave-private; same-wave DS ops are in-order

        // ---- O += P V (single f16 term; V frags from LDS) ----
#pragma unroll
        for (int kk = 0; kk < 2; ++kk) {
            f16x8 pa[2], vf[4];
#pragma unroll
            for (int mi = 0; mi < 2; ++mi)
                pa[mi] = *(const f16x8*)&pt[wave * 32 + mi * 16 + l16][kk * 32 + quad * 8];
#pragma unroll
            for (int dj = 0; dj < 4; ++dj)
                vf[dj] = *(const f16x8*)&vts[dj * 16 + l16][kk * 32 + quad * 8];
#pragma unroll
            for (int mi = 0; mi < 2; ++mi)
#pragma unroll
                for (int dj = 0; dj < 4; ++dj)
                    ao[mi][dj] = mfma16f(pa[mi], vf[dj], ao[mi][dj]);
        }
    }

    // final cross-lane sum, normalize, hardswish, f16 hi-only store
#pragma unroll
    for (int mi = 0; mi < 2; ++mi) {
#pragma unroll
        for (int r = 0; r < 4; ++r) {
            float l = lsum[mi][r];
#pragma unroll
            for (int msk = 1; msk < 16; msk <<= 1)
                l += __shfl_xor(l, msk, 64);
            const float inv = 1.0f / l;
            const int ig = q0 + mi * 16 + quad * 4 + r;
#pragma unroll
            for (int dj = 0; dj < 4; ++dj) {
                const float o = ao[mi][dj][r] * inv;
                const float hsw = o * fminf(fmaxf(o + 3.0f, 0.0f), 6.0f) * (1.0f / 6.0f);
                hsh[((size_t)(b * 1024 + ig)) * 512 + h * 64 + dj * 16 + l16] = (_Float16)hsw;
            }
        }
    }
}

// ---------------------------------------------------------------------------
// K3: output projection GEMM, split-f16 MFMA — 2 TERMS (hs hi-only).
// 64m x 128o tiles, BK=128. NEW: flattened 16-iter (c0,kk) loop with
// software-pipelined B-fragment loads (next iter's woh/wol issued before
// this iter's MFMAs) — VGPR headroom is ample at 2 blocks/CU, no spill risk.
// ---------------------------------------------------------------------------
__global__ __launch_bounds__(256) void out_mfma(
    const _Float16* __restrict__ hsh,
    const _Float16* __restrict__ woh, const _Float16* __restrict__ wol,
    const float* __restrict__ b_out, const float* __restrict__ go, const float* __restrict__ bo,
    const float* __restrict__ mo, const float* __restrict__ vo, float* __restrict__ y)
{
    __shared__ _Float16 Ah[64][136];

    const int t = threadIdx.x;
    const int m0 = blockIdx.x * 64;
    const int o0 = blockIdx.y * 128;
    const int bimg = m0 >> 10, nb = m0 & 1023;
    const int wave = t >> 6, lane = t & 63;
    const int quad = lane >> 4, l16 = lane & 15;
    const int wm = (wave >> 1) * 32, wn = (wave & 1) * 64;

    f32x4 acc[2][4] = {};
    f16x8 bh[4], bl[4], nbh[4], nbl[4];

    // preload B fragments for iteration 0 (c0=0, kk=0)
#pragma unroll
    for (int nj = 0; nj < 4; ++nj) {
        const size_t off = ((size_t)(o0 + wn + nj * 16 + l16)) * 512 + quad * 8;
        bh[nj] = *(const f16x8*)(woh + off);
        bl[nj] = *(const f16x8*)(wol + off);
    }

#pragma unroll
    for (int it = 0; it < 16; ++it) {
        const int c0 = (it >> 2) * 128, kk = it & 3;
        if (kk == 0) {
            __syncthreads();
            const int cs = (t & 7) * 16;
#pragma unroll
            for (int p = 0; p < 2; ++p) {
                const int r = (t >> 3) + p * 32;
                *(f16x8*)&Ah[r][cs]     = *(const f16x8*)(hsh + ((size_t)(m0 + r)) * 512 + c0 + cs);
                *(f16x8*)&Ah[r][cs + 8] = *(const f16x8*)(hsh + ((size_t)(m0 + r)) * 512 + c0 + cs + 8);
            }
            __syncthreads();
        }
        if (it < 15) {   // prefetch next iteration's B fragments
            const int nit = it + 1;
            const int nc0 = (nit >> 2) * 128, nkk = nit & 3;
#pragma unroll
            for (int nj = 0; nj < 4; ++nj) {
                const size_t off = ((size_t)(o0 + wn + nj * 16 + l16)) * 512 + nc0 + nkk * 32 + quad * 8;
                nbh[nj] = *(const f16x8*)(woh + off);
                nbl[nj] = *(const f16x8*)(wol + off);
            }
        }
        f16x8 ah[2];
#pragma unroll
        for (int mi = 0; mi < 2; ++mi)
            ah[mi] = *(const f16x8*)&Ah[wm + mi * 16 + l16][kk * 32 + quad * 8];
#pragma unroll
        for (int mi = 0; mi < 2; ++mi)
#pragma unroll
            for (int nj = 0; nj < 4; ++nj) {
                acc[mi][nj] = mfma16f(ah[mi], bh[nj], acc[mi][nj]);
                acc[mi][nj] = mfma16f(ah[mi], bl[nj], acc[mi][nj]);
            }
#pragma unroll
        for (int nj = 0; nj < 4; ++nj) { bh[nj] = nbh[nj]; bl[nj] = nbl[nj]; }
    }

#pragma unroll
    for (int nj = 0; nj < 4; ++nj) {
        const int o = o0 + wn + nj * 16 + l16;
        const float s = go[o] / sqrtf(vo[o] + 1e-5f);
        const float tt = bo[o] - mo[o] * s;
        const float bf = b_out[o];
#pragma unroll
        for (int mi = 0; mi < 2; ++mi) {
            const int hw = nb + wm + mi * 16 + quad * 4;
            f32x4 v4;
#pragma unroll
            for (int rr = 0; rr < 4; ++rr) v4[rr] = (acc[mi][nj][rr] + bf) * s + tt;
            *(f32x4*)&y[((size_t)(bimg * 256 + o)) * 1024 + hw] = v4;
        }
    }
}

extern "C" void kernel_launch(void* const* d_in, const int* in_sizes, int n_in,
                              void* d_out, int out_size, void* d_ws, size_t ws_size,
                              hipStream_t stream) {
    const float* x     = (const float*)d_in[0];
    const float* wq    = (const float*)d_in[1];
    const float* gq    = (const float*)d_in[2];
    const float* bq    = (const float*)d_in[3];
    const float* mq    = (const float*)d_in[4];
    const float* vq    = (const float*)d_in[5];
    const float* wk    = (const float*)d_in[6];
    const float* gk    = (const float*)d_in[7];
    const float* bk    = (const float*)d_in[8];
    const float* mk    = (const float*)d_in[9];
    const float* vk    = (const float*)d_in[10];
    const float* wv    = (const float*)d_in[11];
    const float* gv    = (const float*)d_in[12];
    const float* bv    = (const float*)d_in[13];
    const float* mv    = (const float*)d_in[14];
    const float* vv    = (const float*)d_in[15];
    const float* emb   = (const float*)d_in[16];
    const float* w_out = (const float*)d_in[17];
    const float* b_out = (const float*)d_in[18];
    const float* go    = (const float*)d_in[19];
    const float* bo    = (const float*)d_in[20];
    const float* mo    = (const float*)d_in[21];
    const float* vo    = (const float*)d_in[22];
    // d_in[23] = pos_indices — computed analytically in-kernel, unused.

    // Workspace (in _Float16 elements); peak < proven 136.3 MB.
    _Float16* us = (_Float16*)d_ws;
    // Union region [0, 16,777,216): xth/xtl early, hsh late (x dead by attn).
    _Float16* xth = us;                        // [16][1024][256]
    _Float16* xtl = us + 4194304;
    _Float16* hsh = us;                        // [16][1024][512] (hi-only)
    _Float16* wsp = us + 16777216;             // weight splits, 8 x 131072
    _Float16* wqh = wsp,            *wql = wsp + 131072;
    _Float16* wkh = wsp + 262144,   *wkl = wsp + 393216;
    _Float16* wvh = wsp + 524288,   *wvl = wsp + 655360;
    _Float16* woh = wsp + 786432,   *wol = wsp + 917504;
    _Float16* qv  = us + 17825792;
    _Float16* qhw = qv,             *qlw = qv + 8388608;   // [16][8][1024][64]
    _Float16* khw = qv + 16777216;                          // [16][8][1024][64] (hi only)
    _Float16* vtw = qv + 33554432;                          // [16][8][64][1024]

    prep<<<6144, 256, 0, stream>>>(x, wq, wk, wv, w_out,
                                   wqh, wql, wkh, wkl, wvh, wvl, woh, wol,
                                   xth, xtl);

    qkv_mfma<<<dim3(12, 128), 256, 0, stream>>>(
        xth, xtl, wqh, wql, wkh, wkl, wvh, wvl,
        gq, bq, mq, vq, gk, bk, mk, vk, gv, bv, mv, vv,
        qhw, qlw, khw, vtw);

    attn_mfma<<<1024, 256, 0, stream>>>(
        qhw, qlw, khw, vtw, emb, hsh);

    out_mfma<<<dim3(256, 2), 256, 0, stream>>>(
        hsh, woh, wol, b_out, go, bo, mo, vo, (float*)d_out);
}